// Round 6
// baseline (213.851 us; speedup 1.0000x reference)
//
#include <hip/hip_runtime.h>

// Problem constants
#define B_   2
#define N_   2048
#define C_   1024
#define H_   16
#define D_   64
#define BH_  (B_*H_)      // 32
#define NDH  (N_*D_)      // 131072 elems per (b,h) plane
#define M1   (B_*N_)      // 4096 rows

typedef __attribute__((ext_vector_type(4))) float    f32x4;
typedef __attribute__((ext_vector_type(8))) _Float16 f16x8;
typedef __attribute__((ext_vector_type(4))) _Float16 f16x4;
typedef __attribute__((ext_vector_type(2))) __fp16   h16x2;

#define GLOAD_LDS(gp, lp) \
  __builtin_amdgcn_global_load_lds((const __attribute__((address_space(1))) void*)(gp), \
                                   (__attribute__((address_space(3))) void*)(lp), 16, 0, 0)

// ---------------- fp32 -> fp16 convert ----------------
__global__ void k_cvt16(const float* __restrict__ in, _Float16* __restrict__ out, int n4) {
  int i = blockIdx.x * blockDim.x + threadIdx.x;
  if (i >= n4) return;
  float4 v = ((const float4*)in)[i];
  f16x4 o;
  o.x = (_Float16)v.x; o.y = (_Float16)v.y; o.z = (_Float16)v.z; o.w = (_Float16)v.w;
  ((f16x4*)out)[i] = o;
}

// --- merged fp32->fp16 transpose for w_qkv and w_proj (+ amax zero-init) ---
__global__ __launch_bounds__(256) void k_transmerge(const float* __restrict__ wq,
                                                    const float* __restrict__ wp,
                                                    _Float16* __restrict__ whT,
                                                    _Float16* __restrict__ wpT,
                                                    unsigned* __restrict__ amax_u) {
  if (blockIdx.x == 0 && threadIdx.x < 64) amax_u[threadIdx.x] = 0u;
  __shared__ _Float16 t[64][68];
  int idx = blockIdx.x;
  const float* in; _Float16* out; int Cc, cx, cy;
  if (idx < 768) { in = wq; out = whT; Cc = 3072; cx = idx % 48; cy = idx / 48; }
  else { idx -= 768; in = wp; out = wpT; Cc = 1024; cx = idx % 16; cy = idx / 16; }
  const int R = 1024;
  int c0 = cx * 64, r0 = cy * 64;
  int tid = threadIdx.x;
  int cq = tid & 15, rq = tid >> 4;
#pragma unroll
  for (int i = 0; i < 4; ++i) {
    int r = rq + i * 16;
    float4 v = *(const float4*)(in + (size_t)(r0 + r) * Cc + c0 + cq * 4);
    t[r][cq*4+0] = (_Float16)v.x;
    t[r][cq*4+1] = (_Float16)v.y;
    t[r][cq*4+2] = (_Float16)v.z;
    t[r][cq*4+3] = (_Float16)v.w;
  }
  __syncthreads();
#pragma unroll
  for (int i = 0; i < 4; ++i) {
    int c = rq + i * 16;
    f16x4 o;
    o.x = t[cq*4+0][c];
    o.y = t[cq*4+1][c];
    o.z = t[cq*4+2][c];
    o.w = t[cq*4+3][c];
    *(f16x4*)(out + (size_t)(c0 + c) * R + r0 + cq * 4) = o;
  }
}

// ---------------- GEMM1: qkv = x @ w_qkv, double-buffered LDS ------------
// R5 post-mortem: stage->sync->compute exposed full stage latency each
// K-step (MfmaUtil 17%, VALUBusy 9%, HBM 13% -> latency-bound). 2-phase
// dbuf: issue next tile's global_load_lds BEFORE computing current tile;
// the end-of-iter __syncthreads (vmcnt drain) lands after the compute.
__global__ __launch_bounds__(256) void k_gemm_qkv(const _Float16* __restrict__ A,
                                                  const _Float16* __restrict__ BT,
                                                  _Float16* __restrict__ qh,
                                                  _Float16* __restrict__ kh,
                                                  _Float16* __restrict__ vh,
                                                  unsigned* __restrict__ amax_u) {
  __shared__ __align__(16) _Float16 As[2][128 * 32];
  __shared__ __align__(16) _Float16 Bs[2][128 * 32];
  const int tid = threadIdx.x, lane = tid & 63, wave = tid >> 6;
  const int wm = wave >> 1, wn = wave & 1;
  const int mcol = lane & 15, quad = lane >> 4;
  const int m0 = blockIdx.x * 128, n0 = blockIdx.y * 128;
  f32x4 acc[4][4] = {};

  auto stage = [&](int buf, int k0) {
#pragma unroll
    for (int r = 0; r < 2; ++r) {
      int c = tid + r * 256;             // 16B chunk id; lane-contiguous LDS dest
      int row = c >> 2, kc = c & 3;
      GLOAD_LDS(A  + (size_t)(m0 + row) * 1024 + k0 + kc * 8, &As[buf][c * 8]);
      GLOAD_LDS(BT + (size_t)(n0 + row) * 1024 + k0 + kc * 8, &Bs[buf][c * 8]);
    }
  };
  auto compute = [&](int buf) {
    f16x8 af[4], bf[4];
#pragma unroll
    for (int tm = 0; tm < 4; ++tm)
      af[tm] = *(const f16x8*)&As[buf][(wm * 64 + tm * 16 + mcol) * 32 + quad * 8];
#pragma unroll
    for (int tn = 0; tn < 4; ++tn)
      bf[tn] = *(const f16x8*)&Bs[buf][(wn * 64 + tn * 16 + mcol) * 32 + quad * 8];
#pragma unroll
    for (int tm = 0; tm < 4; ++tm)
#pragma unroll
      for (int tn = 0; tn < 4; ++tn)
        acc[tm][tn] = __builtin_amdgcn_mfma_f32_16x16x32_f16(af[tm], bf[tn], acc[tm][tn], 0, 0, 0);
  };

  stage(0, 0);
  __syncthreads();
#pragma unroll 1
  for (int k0 = 0; k0 < 1024; k0 += 64) {
    stage(1, k0 + 32);          // in flight during compute(0)
    compute(0);
    __syncthreads();            // drains buf1 loads; all waves done with buf0
    if (k0 + 64 < 1024) stage(0, k0 + 64);
    compute(1);
    __syncthreads();
  }

  const int sec = n0 >> 10;
  if (sec < 2) {
    _Float16* dst = sec ? kh : qh;
    float mxv = 0.f;
#pragma unroll
    for (int tm = 0; tm < 4; ++tm)
#pragma unroll
      for (int tn = 0; tn < 4; ++tn) {
        int rowb = m0 + wm * 64 + tm * 16 + quad * 4;
        int col = n0 + wn * 64 + tn * 16 + mcol;
        int cc = col & 1023, h = cc >> 6, d = cc & 63;
        int b = rowb >> 11, n = rowb & 2047;
        f32x4 a = acc[tm][tn];
        mxv = fmaxf(mxv, fmaxf(fmaxf(fabsf(a[0]), fabsf(a[1])),
                               fmaxf(fabsf(a[2]), fabsf(a[3]))));
        f16x4 o;
        o.x = (_Float16)a[0]; o.y = (_Float16)a[1];
        o.z = (_Float16)a[2]; o.w = (_Float16)a[3];
        *(f16x4*)&dst[(size_t)(b * 16 + h) * 131072 + (size_t)(n >> 5) * 2048 + d * 32 + (n & 31)] = o;
      }
#pragma unroll
    for (int off = 32; off; off >>= 1) mxv = fmaxf(mxv, __shfl_xor(mxv, off));
    if (lane == 0) {
      int head = ((n0 & 1023) >> 6) + wn;
      int plane = (m0 >> 11) * 16 + head;
      atomicMax(&amax_u[sec * 32 + plane], __float_as_uint(mxv));
    }
  } else {
#pragma unroll
    for (int tm = 0; tm < 4; ++tm)
#pragma unroll
      for (int tn = 0; tn < 4; ++tn) {
        int rowb = m0 + wm * 64 + tm * 16 + quad * 4;
        int col = n0 + wn * 64 + tn * 16 + mcol;
        int cc = col & 1023, h = cc >> 6, d = cc & 63;
        int b = rowb >> 11, n = rowb & 2047;
        f16x4 o;
        o.x = (_Float16)acc[tm][tn][0];
        o.y = (_Float16)acc[tm][tn][1];
        o.z = (_Float16)acc[tm][tn][2];
        o.w = (_Float16)acc[tm][tn][3];
        *(f16x4*)&vh[(size_t)(b * 16 + h) * 131072 + (size_t)(n >> 5) * 2048 + d * 32 + (n & 31)] = o;
      }
  }
}

// ---------------- fp8 e4m3 quantize (tiled fp16 in, LDS transpose) -------
// q8 linear [n][d]; k8 permuted MFMA-fragment tiles (same layouts as R4).
__global__ __launch_bounds__(256) void k_quant(const _Float16* __restrict__ qh,
                                               const _Float16* __restrict__ kh,
                                               const float* __restrict__ amax,
                                               char* __restrict__ q8,
                                               char* __restrict__ k8) {
  __shared__ ushort T[32][72];   // 144B rows: 16B-aligned reads
  int blk = blockIdx.x;
  int which = blk >> 11;
  int idx = blk & 2047;
  int bh = idx >> 6, chunk = idx & 63;
  const _Float16* src = (which ? kh : qh) + (size_t)bh * NDH + chunk * 2048;
  float s = 448.f / fmaxf(amax[which * 32 + bh], 1e-12f);
  int t = threadIdx.x;
  // contiguous read: d = t>>2, kk = (t&3)*8 + j
  f16x8 v = *(const f16x8*)(src + t * 8);
  int d = t >> 2, kk0 = (t & 3) * 8;
#pragma unroll
  for (int j = 0; j < 8; ++j) T[kk0 + j][d] = ((const ushort*)&v)[j];
  __syncthreads();
  int r = t >> 3, d0 = (t & 7) * 8;
  f16x8 row = *(const f16x8*)&T[r][d0];
  float f[8];
#pragma unroll
  for (int j = 0; j < 8; ++j) f[j] = (float)((const _Float16*)&row)[j] * s;
  int lo = 0, hi = 0;
  lo = __builtin_amdgcn_cvt_pk_fp8_f32(f[0], f[1], lo, false);
  lo = __builtin_amdgcn_cvt_pk_fp8_f32(f[2], f[3], lo, true);
  hi = __builtin_amdgcn_cvt_pk_fp8_f32(f[4], f[5], hi, false);
  hi = __builtin_amdgcn_cvt_pk_fp8_f32(f[6], f[7], hi, true);
  int2 o; o.x = lo; o.y = hi;
  if (which == 0) {
    char* dst = q8 + (size_t)bh * NDH + (size_t)(chunk * 32 + r) * 64 + d0;
    *(int2*)dst = o;
  } else {
    int e = (r >> 2) & 1;
    int mc = (r >> 3) * 4 + (r & 3);
    int kb = d0 >> 5, dq = (d0 >> 3) & 3;
    char* dst = k8 + (size_t)bh * NDH + chunk * 2048 + (e * 2 + kb) * 512 + mc * 32 + dq * 8;
    *(int2*)dst = o;
  }
}

// ---------------- flash causal attention: block-shared K/V in LDS -------
// 4 waves/block, one 16-row q-group per wave, SAME bh: each 24KB K+V tile
// is staged ONCE per block (global_load_lds, both tiles contiguous in the
// fragment layouts) and consumed by all 4 waves -> 4x less L2 traffic
// (R4 post-mortem: flash was L2-BW/latency-bound at ~835MB of private
// fragment re-reads). Heavy q-groups dispatch first.
__global__ __launch_bounds__(256) void k_flash(const char* __restrict__ q8,
                                               const char* __restrict__ k8,
                                               const _Float16* __restrict__ vh,
                                               const float* __restrict__ amax,
                                               _Float16* __restrict__ attn) {
  const int bh = blockIdx.x;
  const int tid = threadIdx.x;
  const int wave = tid >> 6, lane = tid & 63;
  const int mcol = lane & 15, quad = lane >> 4;
  const int g = 127 - (blockIdx.y * 4 + wave);      // this wave's q-group
  const int nt = (g >> 3) + 1;                      // its causal K-tile count
  const int ntmax = ((127 - blockIdx.y * 4) >> 3) + 1;  // block-max (wave 0)

  __shared__ __align__(16) char     Ks[8192];       // K fp8 tile (128 keys)
  __shared__ __align__(16) _Float16 Vs[8192];       // V fp16 tile (16KB)

  float sq = 448.f / fmaxf(amax[bh], 1e-12f);
  float sk = 448.f / fmaxf(amax[32 + bh], 1e-12f);
  const float c2 = (1.f / (sq * sk)) * 0.125f * 1.44269504089f;  // > 0

  const size_t pbase = (size_t)bh * NDH;
  const char* kpl = k8 + pbase;                     // tile t at +t*8192 bytes
  const _Float16* vpl = vh + pbase;                 // tile t at +t*8192 elems
  const int qrow = g * 16 + mcol;
  long aq0, aq1;
  { const char* qp = q8 + pbase + (size_t)qrow * 64;
    aq0 = *(const long*)(qp + quad * 8); aq1 = *(const long*)(qp + 32 + quad * 8); }

  f32x4 O[4] = {};
  float m_i = -3e38f, l_i = 0.f;   // raw score domain (c2>0 preserves order)
  const int b = bh >> 4, h = bh & 15;
  const int kq = quad * 8;
  const int koff = mcol * 32 + quad * 8;            // bytes into K tile frag
  const int voff = mcol * 32 + quad * 8;            // elems into V tile frag

#pragma unroll 1
  for (int t = 0; t < ntmax; ++t) {
    // ---- stage K (8KB) + V (16KB) for tile t, block-wide ----
    {
      const char* ks = kpl + (size_t)t * 8192;
      const _Float16* vs = vpl + (size_t)t * 8192;
#pragma unroll
      for (int r = 0; r < 2; ++r)
        GLOAD_LDS(ks + (tid + r * 256) * 16, &Ks[(tid + r * 256) * 16]);
#pragma unroll
      for (int r = 0; r < 4; ++r)
        GLOAD_LDS(vs + (tid + r * 256) * 8, &Vs[(tid + r * 256) * 8]);
    }
    __syncthreads();   // drains global_load_lds (vmcnt) + barrier

    if (t < nt) {
      const int n0 = t * 128;
      // ---- QK^T from LDS ----
      f32x4 s[4][2];
#pragma unroll
      for (int p = 0; p < 4; ++p)
#pragma unroll
        for (int e = 0; e < 2; ++e) {
          long ka = *(const long*)&Ks[(p * 4 + e * 2 + 0) * 512 + koff];
          long kb = *(const long*)&Ks[(p * 4 + e * 2 + 1) * 512 + koff];
          f32x4 z = {};
          z = __builtin_amdgcn_mfma_f32_16x16x32_fp8_fp8(ka, aq0, z, 0, 0, 0);
          z = __builtin_amdgcn_mfma_f32_16x16x32_fp8_fp8(kb, aq1, z, 0, 0, 0);
          s[p][e] = z;
        }
      if (t >= nt - 1) {     // last (or beyond-last) tile: causal mask
#pragma unroll
        for (int p = 0; p < 4; ++p)
#pragma unroll
          for (int e = 0; e < 2; ++e)
#pragma unroll
            for (int r = 0; r < 4; ++r) {
              int key = n0 + p * 32 + kq + e * 4 + r;
              s[p][e][r] = (key <= qrow) ? s[p][e][r] : -3e38f;
            }
      }
      // ---- online softmax (raw domain, scale folded into exp2) ----
      float fm[8];
#pragma unroll
      for (int p = 0; p < 4; ++p)
#pragma unroll
        for (int e = 0; e < 2; ++e) {
          f32x4 v = s[p][e];
          fm[p * 2 + e] = fmaxf(fmaxf(v[0], v[1]), fmaxf(v[2], v[3]));
        }
      float mx = fmaxf(fmaxf(fmaxf(fm[0], fm[1]), fmaxf(fm[2], fm[3])),
                       fmaxf(fmaxf(fm[4], fm[5]), fmaxf(fm[6], fm[7])));
      mx = fmaxf(mx, m_i);
      mx = fmaxf(mx, __shfl_xor(mx, 16));
      mx = fmaxf(mx, __shfl_xor(mx, 32));
      float alpha = exp2f((m_i - mx) * c2);
      m_i = mx;
      const float nh = -mx * c2;
      float fs[8];
#pragma unroll
      for (int p = 0; p < 4; ++p)
#pragma unroll
        for (int e = 0; e < 2; ++e) {
          float p0 = exp2f(fmaf(s[p][e][0], c2, nh));
          float p1 = exp2f(fmaf(s[p][e][1], c2, nh));
          float p2 = exp2f(fmaf(s[p][e][2], c2, nh));
          float p3 = exp2f(fmaf(s[p][e][3], c2, nh));
          s[p][e][0] = p0; s[p][e][1] = p1; s[p][e][2] = p2; s[p][e][3] = p3;
          fs[p * 2 + e] = (p0 + p1) + (p2 + p3);
        }
      float sum = ((fs[0] + fs[1]) + (fs[2] + fs[3])) + ((fs[4] + fs[5]) + (fs[6] + fs[7]));
      sum += __shfl_xor(sum, 16);
      sum += __shfl_xor(sum, 32);
      l_i = l_i * alpha + sum;
#pragma unroll
      for (int dt = 0; dt < 4; ++dt)
#pragma unroll
        for (int r = 0; r < 4; ++r)
          O[dt][r] *= alpha;
      // ---- PV from LDS (V fragments loaded per-p to cap liveness) ----
#pragma unroll
      for (int p = 0; p < 4; ++p) {
        f16x8 pb;
        h16x2* pb2 = (h16x2*)&pb;
        pb2[0] = __builtin_amdgcn_cvt_pkrtz(s[p][0][0], s[p][0][1]);
        pb2[1] = __builtin_amdgcn_cvt_pkrtz(s[p][0][2], s[p][0][3]);
        pb2[2] = __builtin_amdgcn_cvt_pkrtz(s[p][1][0], s[p][1][1]);
        pb2[3] = __builtin_amdgcn_cvt_pkrtz(s[p][1][2], s[p][1][3]);
#pragma unroll
        for (int dt = 0; dt < 4; ++dt) {
          f16x8 va = *(const f16x8*)&Vs[p * 2048 + dt * 512 + voff];
          O[dt] = __builtin_amdgcn_mfma_f32_16x16x32_f16(va, pb, O[dt], 0, 0, 0);
        }
      }
    }
    __syncthreads();   // all waves done reading before next tile overwrite
  }

  // ---- epilogue: normalize and store this wave's 16 rows ----
  float rl = 1.f / l_i;
  _Float16* op = attn + ((size_t)b * 2048 + qrow) * 1024 + h * 64;
#pragma unroll
  for (int dt = 0; dt < 4; ++dt) {
    f16x4 o;
    o.x = (_Float16)(O[dt][0] * rl);
    o.y = (_Float16)(O[dt][1] * rl);
    o.z = (_Float16)(O[dt][2] * rl);
    o.w = (_Float16)(O[dt][3] * rl);
    *(f16x4*)(op + dt * 16 + quad * 4) = o;
  }
}

// ---------------- GEMM2: out = attn @ w_proj + b, double-buffered --------
__global__ __launch_bounds__(256) void k_gemm_out(const _Float16* __restrict__ A,
                                                  const _Float16* __restrict__ BT,
                                                  const float* __restrict__ bias,
                                                  float* __restrict__ out) {
  __shared__ __align__(16) _Float16 As[2][128 * 32];
  __shared__ __align__(16) _Float16 Bs[2][128 * 32];
  const int tid = threadIdx.x, lane = tid & 63, wave = tid >> 6;
  const int wm = wave >> 1, wn = wave & 1;
  const int mcol = lane & 15, quad = lane >> 4;
  const int m0 = blockIdx.x * 128, n0 = blockIdx.y * 128;
  f32x4 acc[4][4] = {};

  auto stage = [&](int buf, int k0) {
#pragma unroll
    for (int r = 0; r < 2; ++r) {
      int c = tid + r * 256;
      int row = c >> 2, kc = c & 3;
      GLOAD_LDS(A  + (size_t)(m0 + row) * 1024 + k0 + kc * 8, &As[buf][c * 8]);
      GLOAD_LDS(BT + (size_t)(n0 + row) * 1024 + k0 + kc * 8, &Bs[buf][c * 8]);
    }
  };
  auto compute = [&](int buf) {
    f16x8 af[4], bf[4];
#pragma unroll
    for (int tm = 0; tm < 4; ++tm)
      af[tm] = *(const f16x8*)&As[buf][(wm * 64 + tm * 16 + mcol) * 32 + quad * 8];
#pragma unroll
    for (int tn = 0; tn < 4; ++tn)
      bf[tn] = *(const f16x8*)&Bs[buf][(wn * 64 + tn * 16 + mcol) * 32 + quad * 8];
#pragma unroll
    for (int tm = 0; tm < 4; ++tm)
#pragma unroll
      for (int tn = 0; tn < 4; ++tn)
        acc[tm][tn] = __builtin_amdgcn_mfma_f32_16x16x32_f16(af[tm], bf[tn], acc[tm][tn], 0, 0, 0);
  };

  stage(0, 0);
  __syncthreads();
#pragma unroll 1
  for (int k0 = 0; k0 < 1024; k0 += 64) {
    stage(1, k0 + 32);
    compute(0);
    __syncthreads();
    if (k0 + 64 < 1024) stage(0, k0 + 64);
    compute(1);
    __syncthreads();
  }

#pragma unroll
  for (int tm = 0; tm < 4; ++tm)
#pragma unroll
    for (int tn = 0; tn < 4; ++tn)
#pragma unroll
      for (int reg = 0; reg < 4; ++reg) {
        int row = m0 + wm * 64 + tm * 16 + quad * 4 + reg;
        int col = n0 + wn * 64 + tn * 16 + mcol;
        out[(size_t)row * 1024 + col] = acc[tm][tn][reg] + bias[col];
      }
}

extern "C" void kernel_launch(void* const* d_in, const int* in_sizes, int n_in,
                              void* d_out, int out_size, void* d_ws, size_t ws_size,
                              hipStream_t stream) {
  const float* x      = (const float*)d_in[0];
  const float* w_qkv  = (const float*)d_in[1];
  const float* w_proj = (const float*)d_in[2];
  const float* b_proj = (const float*)d_in[3];
  float* out = (float*)d_out;

  char* ws = (char*)d_ws;
  _Float16* xh   = (_Float16*)ws; ws += (size_t)M1 * C_ * 2;
  _Float16* whT  = (_Float16*)ws; ws += (size_t)3 * C_ * C_ * 2;
  _Float16* wpT  = (_Float16*)ws; ws += (size_t)C_ * C_ * 2;
  _Float16* qh   = (_Float16*)ws; ws += (size_t)BH_ * NDH * 2;
  _Float16* kh   = (_Float16*)ws; ws += (size_t)BH_ * NDH * 2;
  _Float16* vh   = (_Float16*)ws; ws += (size_t)BH_ * NDH * 2;
  char*     q8   = (char*)ws;     ws += (size_t)BH_ * NDH;
  char*     k8   = (char*)ws;     ws += (size_t)BH_ * NDH;
  _Float16* attn = (_Float16*)ws; ws += (size_t)M1 * C_ * 2;
  float*    amx  = (float*)ws;    ws += 256;

  k_cvt16<<<(M1 * C_ / 4 + 255) / 256, 256, 0, stream>>>(x, xh, M1 * C_ / 4);
  k_transmerge<<<1024, 256, 0, stream>>>(w_qkv, w_proj, whT, wpT, (unsigned*)amx);
  k_gemm_qkv<<<dim3(M1 / 128, 3 * C_ / 128), 256, 0, stream>>>(xh, whT, qh, kh, vh, (unsigned*)amx);
  k_quant<<<4096, 256, 0, stream>>>(qh, kh, amx, q8, k8);
  k_flash<<<dim3(32, 32), 256, 0, stream>>>(q8, k8, vh, amx, attn);
  k_gemm_out<<<dim3(M1 / 128, C_ / 128), 256, 0, stream>>>(attn, wpT, b_proj, out);
}

// Round 7
// 204.346 us; speedup vs baseline: 1.0465x; 1.0465x over previous
//
#include <hip/hip_runtime.h>

// Problem constants
#define B_   2
#define N_   2048
#define C_   1024
#define H_   16
#define D_   64
#define BH_  (B_*H_)      // 32
#define NDH  (N_*D_)      // 131072 elems per (b,h) plane
#define M1   (B_*N_)      // 4096 rows

typedef __attribute__((ext_vector_type(4))) float    f32x4;
typedef __attribute__((ext_vector_type(8))) _Float16 f16x8;
typedef __attribute__((ext_vector_type(4))) _Float16 f16x4;
typedef __attribute__((ext_vector_type(2))) __fp16   h16x2;

#define GLOAD_LDS(gp, lp) \
  __builtin_amdgcn_global_load_lds((const __attribute__((address_space(1))) void*)(gp), \
                                   (__attribute__((address_space(3))) void*)(lp), 16, 0, 0)

// ---- merged prep: fp32->fp16 convert of x (blocks 0..4095) +
//      fp32->fp16 transpose of w_qkv/w_proj + amax zero-init (4096..5119) ----
__global__ __launch_bounds__(256) void k_prep(const float* __restrict__ x,
                                              _Float16* __restrict__ xh,
                                              const float* __restrict__ wq,
                                              const float* __restrict__ wp,
                                              _Float16* __restrict__ whT,
                                              _Float16* __restrict__ wpT,
                                              unsigned* __restrict__ amax_u) {
  __shared__ _Float16 t[64][68];
  int bid = blockIdx.x;
  if (bid < 4096) {
    int i = bid * 256 + threadIdx.x;       // n4 = 4096*256 exactly
    float4 v = ((const float4*)x)[i];
    f16x4 o;
    o.x = (_Float16)v.x; o.y = (_Float16)v.y; o.z = (_Float16)v.z; o.w = (_Float16)v.w;
    ((f16x4*)xh)[i] = o;
    return;
  }
  int idx = bid - 4096;
  if (idx == 0 && threadIdx.x < 64) amax_u[threadIdx.x] = 0u;
  const float* in; _Float16* out; int Cc, cx, cy;
  if (idx < 768) { in = wq; out = whT; Cc = 3072; cx = idx % 48; cy = idx / 48; }
  else { idx -= 768; in = wp; out = wpT; Cc = 1024; cx = idx % 16; cy = idx / 16; }
  const int R = 1024;
  int c0 = cx * 64, r0 = cy * 64;
  int tid = threadIdx.x;
  int cq = tid & 15, rq = tid >> 4;
#pragma unroll
  for (int i = 0; i < 4; ++i) {
    int r = rq + i * 16;
    float4 v = *(const float4*)(in + (size_t)(r0 + r) * Cc + c0 + cq * 4);
    t[r][cq*4+0] = (_Float16)v.x;
    t[r][cq*4+1] = (_Float16)v.y;
    t[r][cq*4+2] = (_Float16)v.z;
    t[r][cq*4+3] = (_Float16)v.w;
  }
  __syncthreads();
#pragma unroll
  for (int i = 0; i < 4; ++i) {
    int c = rq + i * 16;
    f16x4 o;
    o.x = t[cq*4+0][c];
    o.y = t[cq*4+1][c];
    o.z = t[cq*4+2][c];
    o.w = t[cq*4+3][c];
    *(f16x4*)(out + (size_t)(c0 + c) * R + r0 + cq * 4) = o;
  }
}

// ---------------- GEMM1: qkv = x @ w_qkv ---------------------------------
// R6 post-mortem: dbuf null (barrier drains vmcnt(0) anyway). BK=64
// single-buffer halves the drain count; XOR-swizzled staging (linear LDS
// dest + pre-swizzled global source, same XOR on reads) kills the
// 16-way bank conflict a 128B-row layout would have.
__global__ __launch_bounds__(256) void k_gemm_qkv(const _Float16* __restrict__ A,
                                                  const _Float16* __restrict__ BT,
                                                  _Float16* __restrict__ qh,
                                                  _Float16* __restrict__ kh,
                                                  _Float16* __restrict__ vh,
                                                  unsigned* __restrict__ amax_u) {
  __shared__ __align__(16) _Float16 As[128 * 64];
  __shared__ __align__(16) _Float16 Bs[128 * 64];
  const int tid = threadIdx.x, lane = tid & 63, wave = tid >> 6;
  const int wm = wave >> 1, wn = wave & 1;
  const int mcol = lane & 15, quad = lane >> 4;
  const int m0 = blockIdx.x * 128, n0 = blockIdx.y * 128;
  const int swa = mcol & 7;                 // row&7 for all this lane's frag rows
  f32x4 acc[4][4] = {};

#pragma unroll 1
  for (int k0 = 0; k0 < 1024; k0 += 64) {
#pragma unroll
    for (int r = 0; r < 4; ++r) {
      int s = tid + r * 256;                // LDS slot (16B), linear dest
      int row = s >> 3, kc = (s & 7) ^ (row & 7);   // pre-swizzled source chunk
      GLOAD_LDS(A  + (size_t)(m0 + row) * 1024 + k0 + kc * 8, &As[s * 8]);
      GLOAD_LDS(BT + (size_t)(n0 + row) * 1024 + k0 + kc * 8, &Bs[s * 8]);
    }
    __syncthreads();
#pragma unroll
    for (int kk = 0; kk < 2; ++kk) {
      f16x8 af[4], bf[4];
#pragma unroll
      for (int tm = 0; tm < 4; ++tm) {
        int row = wm * 64 + tm * 16 + mcol;
        af[tm] = *(const f16x8*)&As[(row * 8 + ((kk * 4 + quad) ^ swa)) * 8];
      }
#pragma unroll
      for (int tn = 0; tn < 4; ++tn) {
        int row = wn * 64 + tn * 16 + mcol;
        bf[tn] = *(const f16x8*)&Bs[(row * 8 + ((kk * 4 + quad) ^ swa)) * 8];
      }
#pragma unroll
      for (int tm = 0; tm < 4; ++tm)
#pragma unroll
        for (int tn = 0; tn < 4; ++tn)
          acc[tm][tn] = __builtin_amdgcn_mfma_f32_16x16x32_f16(af[tm], bf[tn], acc[tm][tn], 0, 0, 0);
    }
    __syncthreads();
  }

  const int sec = n0 >> 10;
  if (sec < 2) {
    _Float16* dst = sec ? kh : qh;
    float mxv = 0.f;
#pragma unroll
    for (int tm = 0; tm < 4; ++tm)
#pragma unroll
      for (int tn = 0; tn < 4; ++tn) {
        int rowb = m0 + wm * 64 + tm * 16 + quad * 4;
        int col = n0 + wn * 64 + tn * 16 + mcol;
        int cc = col & 1023, h = cc >> 6, d = cc & 63;
        int b = rowb >> 11, n = rowb & 2047;
        f32x4 a = acc[tm][tn];
        mxv = fmaxf(mxv, fmaxf(fmaxf(fabsf(a[0]), fabsf(a[1])),
                               fmaxf(fabsf(a[2]), fabsf(a[3]))));
        f16x4 o;
        o.x = (_Float16)a[0]; o.y = (_Float16)a[1];
        o.z = (_Float16)a[2]; o.w = (_Float16)a[3];
        *(f16x4*)&dst[(size_t)(b * 16 + h) * 131072 + (size_t)(n >> 5) * 2048 + d * 32 + (n & 31)] = o;
      }
#pragma unroll
    for (int off = 32; off; off >>= 1) mxv = fmaxf(mxv, __shfl_xor(mxv, off));
    if (lane == 0) {
      int head = ((n0 & 1023) >> 6) + wn;
      int plane = (m0 >> 11) * 16 + head;
      atomicMax(&amax_u[sec * 32 + plane], __float_as_uint(mxv));
    }
  } else {
#pragma unroll
    for (int tm = 0; tm < 4; ++tm)
#pragma unroll
      for (int tn = 0; tn < 4; ++tn) {
        int rowb = m0 + wm * 64 + tm * 16 + quad * 4;
        int col = n0 + wn * 64 + tn * 16 + mcol;
        int cc = col & 1023, h = cc >> 6, d = cc & 63;
        int b = rowb >> 11, n = rowb & 2047;
        f16x4 o;
        o.x = (_Float16)acc[tm][tn][0];
        o.y = (_Float16)acc[tm][tn][1];
        o.z = (_Float16)acc[tm][tn][2];
        o.w = (_Float16)acc[tm][tn][3];
        *(f16x4*)&vh[(size_t)(b * 16 + h) * 131072 + (size_t)(n >> 5) * 2048 + d * 32 + (n & 31)] = o;
      }
  }
}

// ---------------- fp8 e4m3 quantize (tiled fp16 in, LDS transpose) -------
__global__ __launch_bounds__(256) void k_quant(const _Float16* __restrict__ qh,
                                               const _Float16* __restrict__ kh,
                                               const float* __restrict__ amax,
                                               char* __restrict__ q8,
                                               char* __restrict__ k8) {
  __shared__ ushort T[32][72];   // 144B rows: 16B-aligned reads
  int blk = blockIdx.x;
  int which = blk >> 11;
  int idx = blk & 2047;
  int bh = idx >> 6, chunk = idx & 63;
  const _Float16* src = (which ? kh : qh) + (size_t)bh * NDH + chunk * 2048;
  float s = 448.f / fmaxf(amax[which * 32 + bh], 1e-12f);
  int t = threadIdx.x;
  f16x8 v = *(const f16x8*)(src + t * 8);
  int d = t >> 2, kk0 = (t & 3) * 8;
#pragma unroll
  for (int j = 0; j < 8; ++j) T[kk0 + j][d] = ((const ushort*)&v)[j];
  __syncthreads();
  int r = t >> 3, d0 = (t & 7) * 8;
  f16x8 row = *(const f16x8*)&T[r][d0];
  float f[8];
#pragma unroll
  for (int j = 0; j < 8; ++j) f[j] = (float)((const _Float16*)&row)[j] * s;
  int lo = 0, hi = 0;
  lo = __builtin_amdgcn_cvt_pk_fp8_f32(f[0], f[1], lo, false);
  lo = __builtin_amdgcn_cvt_pk_fp8_f32(f[2], f[3], lo, true);
  hi = __builtin_amdgcn_cvt_pk_fp8_f32(f[4], f[5], hi, false);
  hi = __builtin_amdgcn_cvt_pk_fp8_f32(f[6], f[7], hi, true);
  int2 o; o.x = lo; o.y = hi;
  if (which == 0) {
    char* dst = q8 + (size_t)bh * NDH + (size_t)(chunk * 32 + r) * 64 + d0;
    *(int2*)dst = o;
  } else {
    int e = (r >> 2) & 1;
    int mc = (r >> 3) * 4 + (r & 3);
    int kb = d0 >> 5, dq = (d0 >> 3) & 3;
    char* dst = k8 + (size_t)bh * NDH + chunk * 2048 + (e * 2 + kb) * 512 + mc * 32 + dq * 8;
    *(int2*)dst = o;
  }
}

// ---------------- flash causal attention: block-shared K/V in LDS -------
__global__ __launch_bounds__(256) void k_flash(const char* __restrict__ q8,
                                               const char* __restrict__ k8,
                                               const _Float16* __restrict__ vh,
                                               const float* __restrict__ amax,
                                               _Float16* __restrict__ attn) {
  const int bh = blockIdx.x;
  const int tid = threadIdx.x;
  const int wave = tid >> 6, lane = tid & 63;
  const int mcol = lane & 15, quad = lane >> 4;
  const int g = 127 - (blockIdx.y * 4 + wave);      // this wave's q-group
  const int nt = (g >> 3) + 1;                      // its causal K-tile count
  const int ntmax = ((127 - blockIdx.y * 4) >> 3) + 1;  // block-max (wave 0)

  __shared__ __align__(16) char     Ks[8192];       // K fp8 tile (128 keys)
  __shared__ __align__(16) _Float16 Vs[8192];       // V fp16 tile (16KB)

  float sq = 448.f / fmaxf(amax[bh], 1e-12f);
  float sk = 448.f / fmaxf(amax[32 + bh], 1e-12f);
  const float c2 = (1.f / (sq * sk)) * 0.125f * 1.44269504089f;  // > 0

  const size_t pbase = (size_t)bh * NDH;
  const char* kpl = k8 + pbase;
  const _Float16* vpl = vh + pbase;
  const int qrow = g * 16 + mcol;
  long aq0, aq1;
  { const char* qp = q8 + pbase + (size_t)qrow * 64;
    aq0 = *(const long*)(qp + quad * 8); aq1 = *(const long*)(qp + 32 + quad * 8); }

  f32x4 O[4] = {};
  float m_i = -3e38f, l_i = 0.f;
  const int b = bh >> 4, h = bh & 15;
  const int kq = quad * 8;
  const int koff = mcol * 32 + quad * 8;
  const int voff = mcol * 32 + quad * 8;

#pragma unroll 1
  for (int t = 0; t < ntmax; ++t) {
    {
      const char* ks = kpl + (size_t)t * 8192;
      const _Float16* vs = vpl + (size_t)t * 8192;
#pragma unroll
      for (int r = 0; r < 2; ++r)
        GLOAD_LDS(ks + (tid + r * 256) * 16, &Ks[(tid + r * 256) * 16]);
#pragma unroll
      for (int r = 0; r < 4; ++r)
        GLOAD_LDS(vs + (tid + r * 256) * 8, &Vs[(tid + r * 256) * 8]);
    }
    __syncthreads();

    if (t < nt) {
      const int n0 = t * 128;
      f32x4 s[4][2];
#pragma unroll
      for (int p = 0; p < 4; ++p)
#pragma unroll
        for (int e = 0; e < 2; ++e) {
          long ka = *(const long*)&Ks[(p * 4 + e * 2 + 0) * 512 + koff];
          long kb = *(const long*)&Ks[(p * 4 + e * 2 + 1) * 512 + koff];
          f32x4 z = {};
          z = __builtin_amdgcn_mfma_f32_16x16x32_fp8_fp8(ka, aq0, z, 0, 0, 0);
          z = __builtin_amdgcn_mfma_f32_16x16x32_fp8_fp8(kb, aq1, z, 0, 0, 0);
          s[p][e] = z;
        }
      if (t >= nt - 1) {
#pragma unroll
        for (int p = 0; p < 4; ++p)
#pragma unroll
          for (int e = 0; e < 2; ++e)
#pragma unroll
            for (int r = 0; r < 4; ++r) {
              int key = n0 + p * 32 + kq + e * 4 + r;
              s[p][e][r] = (key <= qrow) ? s[p][e][r] : -3e38f;
            }
      }
      float fm[8];
#pragma unroll
      for (int p = 0; p < 4; ++p)
#pragma unroll
        for (int e = 0; e < 2; ++e) {
          f32x4 v = s[p][e];
          fm[p * 2 + e] = fmaxf(fmaxf(v[0], v[1]), fmaxf(v[2], v[3]));
        }
      float mx = fmaxf(fmaxf(fmaxf(fm[0], fm[1]), fmaxf(fm[2], fm[3])),
                       fmaxf(fmaxf(fm[4], fm[5]), fmaxf(fm[6], fm[7])));
      mx = fmaxf(mx, m_i);
      mx = fmaxf(mx, __shfl_xor(mx, 16));
      mx = fmaxf(mx, __shfl_xor(mx, 32));
      float alpha = exp2f((m_i - mx) * c2);
      m_i = mx;
      const float nh = -mx * c2;
      float fs[8];
#pragma unroll
      for (int p = 0; p < 4; ++p)
#pragma unroll
        for (int e = 0; e < 2; ++e) {
          float p0 = exp2f(fmaf(s[p][e][0], c2, nh));
          float p1 = exp2f(fmaf(s[p][e][1], c2, nh));
          float p2 = exp2f(fmaf(s[p][e][2], c2, nh));
          float p3 = exp2f(fmaf(s[p][e][3], c2, nh));
          s[p][e][0] = p0; s[p][e][1] = p1; s[p][e][2] = p2; s[p][e][3] = p3;
          fs[p * 2 + e] = (p0 + p1) + (p2 + p3);
        }
      float sum = ((fs[0] + fs[1]) + (fs[2] + fs[3])) + ((fs[4] + fs[5]) + (fs[6] + fs[7]));
      sum += __shfl_xor(sum, 16);
      sum += __shfl_xor(sum, 32);
      l_i = l_i * alpha + sum;
#pragma unroll
      for (int dt = 0; dt < 4; ++dt)
#pragma unroll
        for (int r = 0; r < 4; ++r)
          O[dt][r] *= alpha;
#pragma unroll
      for (int p = 0; p < 4; ++p) {
        f16x8 pb;
        h16x2* pb2 = (h16x2*)&pb;
        pb2[0] = __builtin_amdgcn_cvt_pkrtz(s[p][0][0], s[p][0][1]);
        pb2[1] = __builtin_amdgcn_cvt_pkrtz(s[p][0][2], s[p][0][3]);
        pb2[2] = __builtin_amdgcn_cvt_pkrtz(s[p][1][0], s[p][1][1]);
        pb2[3] = __builtin_amdgcn_cvt_pkrtz(s[p][1][2], s[p][1][3]);
#pragma unroll
        for (int dt = 0; dt < 4; ++dt) {
          f16x8 va = *(const f16x8*)&Vs[p * 2048 + dt * 512 + voff];
          O[dt] = __builtin_amdgcn_mfma_f32_16x16x32_f16(va, pb, O[dt], 0, 0, 0);
        }
      }
    }
    __syncthreads();
  }

  float rl = 1.f / l_i;
  _Float16* op = attn + ((size_t)b * 2048 + qrow) * 1024 + h * 64;
#pragma unroll
  for (int dt = 0; dt < 4; ++dt) {
    f16x4 o;
    o.x = (_Float16)(O[dt][0] * rl);
    o.y = (_Float16)(O[dt][1] * rl);
    o.z = (_Float16)(O[dt][2] * rl);
    o.w = (_Float16)(O[dt][3] * rl);
    *(f16x4*)(op + dt * 16 + quad * 4) = o;
  }
}

// ---------------- GEMM2: out = attn @ w_proj + b (BK=64 + swizzle) -------
__global__ __launch_bounds__(256) void k_gemm_out(const _Float16* __restrict__ A,
                                                  const _Float16* __restrict__ BT,
                                                  const float* __restrict__ bias,
                                                  float* __restrict__ out) {
  __shared__ __align__(16) _Float16 As[128 * 64];
  __shared__ __align__(16) _Float16 Bs[128 * 64];
  const int tid = threadIdx.x, lane = tid & 63, wave = tid >> 6;
  const int wm = wave >> 1, wn = wave & 1;
  const int mcol = lane & 15, quad = lane >> 4;
  const int m0 = blockIdx.x * 128, n0 = blockIdx.y * 128;
  const int swa = mcol & 7;
  f32x4 acc[4][4] = {};

#pragma unroll 1
  for (int k0 = 0; k0 < 1024; k0 += 64) {
#pragma unroll
    for (int r = 0; r < 4; ++r) {
      int s = tid + r * 256;
      int row = s >> 3, kc = (s & 7) ^ (row & 7);
      GLOAD_LDS(A  + (size_t)(m0 + row) * 1024 + k0 + kc * 8, &As[s * 8]);
      GLOAD_LDS(BT + (size_t)(n0 + row) * 1024 + k0 + kc * 8, &Bs[s * 8]);
    }
    __syncthreads();
#pragma unroll
    for (int kk = 0; kk < 2; ++kk) {
      f16x8 af[4], bf[4];
#pragma unroll
      for (int tm = 0; tm < 4; ++tm) {
        int row = wm * 64 + tm * 16 + mcol;
        af[tm] = *(const f16x8*)&As[(row * 8 + ((kk * 4 + quad) ^ swa)) * 8];
      }
#pragma unroll
      for (int tn = 0; tn < 4; ++tn) {
        int row = wn * 64 + tn * 16 + mcol;
        bf[tn] = *(const f16x8*)&Bs[(row * 8 + ((kk * 4 + quad) ^ swa)) * 8];
      }
#pragma unroll
      for (int tm = 0; tm < 4; ++tm)
#pragma unroll
        for (int tn = 0; tn < 4; ++tn)
          acc[tm][tn] = __builtin_amdgcn_mfma_f32_16x16x32_f16(af[tm], bf[tn], acc[tm][tn], 0, 0, 0);
    }
    __syncthreads();
  }

#pragma unroll
  for (int tm = 0; tm < 4; ++tm)
#pragma unroll
    for (int tn = 0; tn < 4; ++tn)
#pragma unroll
      for (int reg = 0; reg < 4; ++reg) {
        int row = m0 + wm * 64 + tm * 16 + quad * 4 + reg;
        int col = n0 + wn * 64 + tn * 16 + mcol;
        out[(size_t)row * 1024 + col] = acc[tm][tn][reg] + bias[col];
      }
}

extern "C" void kernel_launch(void* const* d_in, const int* in_sizes, int n_in,
                              void* d_out, int out_size, void* d_ws, size_t ws_size,
                              hipStream_t stream) {
  const float* x      = (const float*)d_in[0];
  const float* w_qkv  = (const float*)d_in[1];
  const float* w_proj = (const float*)d_in[2];
  const float* b_proj = (const float*)d_in[3];
  float* out = (float*)d_out;

  char* ws = (char*)d_ws;
  _Float16* xh   = (_Float16*)ws; ws += (size_t)M1 * C_ * 2;
  _Float16* whT  = (_Float16*)ws; ws += (size_t)3 * C_ * C_ * 2;
  _Float16* wpT  = (_Float16*)ws; ws += (size_t)C_ * C_ * 2;
  _Float16* qh   = (_Float16*)ws; ws += (size_t)BH_ * NDH * 2;
  _Float16* kh   = (_Float16*)ws; ws += (size_t)BH_ * NDH * 2;
  _Float16* vh   = (_Float16*)ws; ws += (size_t)BH_ * NDH * 2;
  char*     q8   = (char*)ws;     ws += (size_t)BH_ * NDH;
  char*     k8   = (char*)ws;     ws += (size_t)BH_ * NDH;
  _Float16* attn = (_Float16*)ws; ws += (size_t)M1 * C_ * 2;
  float*    amx  = (float*)ws;    ws += 256;

  k_prep<<<5120, 256, 0, stream>>>(x, xh, w_qkv, w_proj, whT, wpT, (unsigned*)amx);
  k_gemm_qkv<<<dim3(M1 / 128, 3 * C_ / 128), 256, 0, stream>>>(xh, whT, qh, kh, vh, (unsigned*)amx);
  k_quant<<<4096, 256, 0, stream>>>(qh, kh, amx, q8, k8);
  k_flash<<<dim3(32, 32), 256, 0, stream>>>(q8, k8, vh, amx, attn);
  k_gemm_out<<<dim3(M1 / 128, C_ / 128), 256, 0, stream>>>(attn, wpT, b_proj, out);
}

// Round 8
// 200.771 us; speedup vs baseline: 1.0652x; 1.0178x over previous
//
#include <hip/hip_runtime.h>

// Problem constants
#define B_   2
#define N_   2048
#define C_   1024
#define H_   16
#define D_   64
#define BH_  (B_*H_)      // 32
#define NDH  (N_*D_)      // 131072 elems per (b,h) plane
#define M1   (B_*N_)      // 4096 rows

typedef __attribute__((ext_vector_type(4))) float    f32x4;
typedef __attribute__((ext_vector_type(8))) _Float16 f16x8;
typedef __attribute__((ext_vector_type(4))) _Float16 f16x4;
typedef __attribute__((ext_vector_type(2))) __fp16   h16x2;

#define GLOAD_LDS(gp, lp) \
  __builtin_amdgcn_global_load_lds((const __attribute__((address_space(1))) void*)(gp), \
                                   (__attribute__((address_space(3))) void*)(lp), 16, 0, 0)

// ---- merged prep: fp32->fp16 convert of x (blocks 0..4095) +
//      fp32->fp16 transpose of w_qkv/w_proj + amax zero-init (4096..5119) ----
__global__ __launch_bounds__(256) void k_prep(const float* __restrict__ x,
                                              _Float16* __restrict__ xh,
                                              const float* __restrict__ wq,
                                              const float* __restrict__ wp,
                                              _Float16* __restrict__ whT,
                                              _Float16* __restrict__ wpT,
                                              unsigned* __restrict__ amax_u) {
  __shared__ _Float16 t[64][68];
  int bid = blockIdx.x;
  if (bid < 4096) {
    int i = bid * 256 + threadIdx.x;       // n4 = 4096*256 exactly
    float4 v = ((const float4*)x)[i];
    f16x4 o;
    o.x = (_Float16)v.x; o.y = (_Float16)v.y; o.z = (_Float16)v.z; o.w = (_Float16)v.w;
    ((f16x4*)xh)[i] = o;
    return;
  }
  int idx = bid - 4096;
  if (idx == 0 && threadIdx.x < 64) amax_u[threadIdx.x] = 0u;
  const float* in; _Float16* out; int Cc, cx, cy;
  if (idx < 768) { in = wq; out = whT; Cc = 3072; cx = idx % 48; cy = idx / 48; }
  else { idx -= 768; in = wp; out = wpT; Cc = 1024; cx = idx % 16; cy = idx / 16; }
  const int R = 1024;
  int c0 = cx * 64, r0 = cy * 64;
  int tid = threadIdx.x;
  int cq = tid & 15, rq = tid >> 4;
#pragma unroll
  for (int i = 0; i < 4; ++i) {
    int r = rq + i * 16;
    float4 v = *(const float4*)(in + (size_t)(r0 + r) * Cc + c0 + cq * 4);
    t[r][cq*4+0] = (_Float16)v.x;
    t[r][cq*4+1] = (_Float16)v.y;
    t[r][cq*4+2] = (_Float16)v.z;
    t[r][cq*4+3] = (_Float16)v.w;
  }
  __syncthreads();
#pragma unroll
  for (int i = 0; i < 4; ++i) {
    int c = rq + i * 16;
    f16x4 o;
    o.x = t[cq*4+0][c];
    o.y = t[cq*4+1][c];
    o.z = t[cq*4+2][c];
    o.w = t[cq*4+3][c];
    *(f16x4*)(out + (size_t)(c0 + c) * R + r0 + cq * 4) = o;
  }
}

// ---------------- GEMM1: qkv = x @ w_qkv (BK=64 + XOR swizzle) -----------
__global__ __launch_bounds__(256) void k_gemm_qkv(const _Float16* __restrict__ A,
                                                  const _Float16* __restrict__ BT,
                                                  _Float16* __restrict__ qh,
                                                  _Float16* __restrict__ kh,
                                                  _Float16* __restrict__ vh,
                                                  unsigned* __restrict__ amax_u) {
  __shared__ __align__(16) _Float16 As[128 * 64];
  __shared__ __align__(16) _Float16 Bs[128 * 64];
  const int tid = threadIdx.x, lane = tid & 63, wave = tid >> 6;
  const int wm = wave >> 1, wn = wave & 1;
  const int mcol = lane & 15, quad = lane >> 4;
  const int m0 = blockIdx.x * 128, n0 = blockIdx.y * 128;
  const int swa = mcol & 7;                 // row&7 for all this lane's frag rows
  f32x4 acc[4][4] = {};

#pragma unroll 1
  for (int k0 = 0; k0 < 1024; k0 += 64) {
#pragma unroll
    for (int r = 0; r < 4; ++r) {
      int s = tid + r * 256;                // LDS slot (16B), linear dest
      int row = s >> 3, kc = (s & 7) ^ (row & 7);   // pre-swizzled source chunk
      GLOAD_LDS(A  + (size_t)(m0 + row) * 1024 + k0 + kc * 8, &As[s * 8]);
      GLOAD_LDS(BT + (size_t)(n0 + row) * 1024 + k0 + kc * 8, &Bs[s * 8]);
    }
    __syncthreads();
#pragma unroll
    for (int kk = 0; kk < 2; ++kk) {
      f16x8 af[4], bf[4];
#pragma unroll
      for (int tm = 0; tm < 4; ++tm) {
        int row = wm * 64 + tm * 16 + mcol;
        af[tm] = *(const f16x8*)&As[(row * 8 + ((kk * 4 + quad) ^ swa)) * 8];
      }
#pragma unroll
      for (int tn = 0; tn < 4; ++tn) {
        int row = wn * 64 + tn * 16 + mcol;
        bf[tn] = *(const f16x8*)&Bs[(row * 8 + ((kk * 4 + quad) ^ swa)) * 8];
      }
#pragma unroll
      for (int tm = 0; tm < 4; ++tm)
#pragma unroll
        for (int tn = 0; tn < 4; ++tn)
          acc[tm][tn] = __builtin_amdgcn_mfma_f32_16x16x32_f16(af[tm], bf[tn], acc[tm][tn], 0, 0, 0);
    }
    __syncthreads();
  }

  const int sec = n0 >> 10;
  if (sec < 2) {
    _Float16* dst = sec ? kh : qh;
    float mxv = 0.f;
#pragma unroll
    for (int tm = 0; tm < 4; ++tm)
#pragma unroll
      for (int tn = 0; tn < 4; ++tn) {
        int rowb = m0 + wm * 64 + tm * 16 + quad * 4;
        int col = n0 + wn * 64 + tn * 16 + mcol;
        int cc = col & 1023, h = cc >> 6, d = cc & 63;
        int b = rowb >> 11, n = rowb & 2047;
        f32x4 a = acc[tm][tn];
        mxv = fmaxf(mxv, fmaxf(fmaxf(fabsf(a[0]), fabsf(a[1])),
                               fmaxf(fabsf(a[2]), fabsf(a[3]))));
        f16x4 o;
        o.x = (_Float16)a[0]; o.y = (_Float16)a[1];
        o.z = (_Float16)a[2]; o.w = (_Float16)a[3];
        *(f16x4*)&dst[(size_t)(b * 16 + h) * 131072 + (size_t)(n >> 5) * 2048 + d * 32 + (n & 31)] = o;
      }
#pragma unroll
    for (int off = 32; off; off >>= 1) mxv = fmaxf(mxv, __shfl_xor(mxv, off));
    if (lane == 0) {
      int head = ((n0 & 1023) >> 6) + wn;
      int plane = (m0 >> 11) * 16 + head;
      atomicMax(&amax_u[sec * 32 + plane], __float_as_uint(mxv));
    }
  } else {
#pragma unroll
    for (int tm = 0; tm < 4; ++tm)
#pragma unroll
      for (int tn = 0; tn < 4; ++tn) {
        int rowb = m0 + wm * 64 + tm * 16 + quad * 4;
        int col = n0 + wn * 64 + tn * 16 + mcol;
        int cc = col & 1023, h = cc >> 6, d = cc & 63;
        int b = rowb >> 11, n = rowb & 2047;
        f16x4 o;
        o.x = (_Float16)acc[tm][tn][0];
        o.y = (_Float16)acc[tm][tn][1];
        o.z = (_Float16)acc[tm][tn][2];
        o.w = (_Float16)acc[tm][tn][3];
        *(f16x4*)&vh[(size_t)(b * 16 + h) * 131072 + (size_t)(n >> 5) * 2048 + d * 32 + (n & 31)] = o;
      }
  }
}

// ---------------- fp8 e4m3 quantize (tiled fp16 in, LDS transpose) -------
__global__ __launch_bounds__(256) void k_quant(const _Float16* __restrict__ qh,
                                               const _Float16* __restrict__ kh,
                                               const float* __restrict__ amax,
                                               char* __restrict__ q8,
                                               char* __restrict__ k8) {
  __shared__ ushort T[32][72];   // 144B rows: 16B-aligned reads
  int blk = blockIdx.x;
  int which = blk >> 11;
  int idx = blk & 2047;
  int bh = idx >> 6, chunk = idx & 63;
  const _Float16* src = (which ? kh : qh) + (size_t)bh * NDH + chunk * 2048;
  float s = 448.f / fmaxf(amax[which * 32 + bh], 1e-12f);
  int t = threadIdx.x;
  f16x8 v = *(const f16x8*)(src + t * 8);
  int d = t >> 2, kk0 = (t & 3) * 8;
#pragma unroll
  for (int j = 0; j < 8; ++j) T[kk0 + j][d] = ((const ushort*)&v)[j];
  __syncthreads();
  int r = t >> 3, d0 = (t & 7) * 8;
  f16x8 row = *(const f16x8*)&T[r][d0];
  float f[8];
#pragma unroll
  for (int j = 0; j < 8; ++j) f[j] = (float)((const _Float16*)&row)[j] * s;
  int lo = 0, hi = 0;
  lo = __builtin_amdgcn_cvt_pk_fp8_f32(f[0], f[1], lo, false);
  lo = __builtin_amdgcn_cvt_pk_fp8_f32(f[2], f[3], lo, true);
  hi = __builtin_amdgcn_cvt_pk_fp8_f32(f[4], f[5], hi, false);
  hi = __builtin_amdgcn_cvt_pk_fp8_f32(f[6], f[7], hi, true);
  int2 o; o.x = lo; o.y = hi;
  if (which == 0) {
    char* dst = q8 + (size_t)bh * NDH + (size_t)(chunk * 32 + r) * 64 + d0;
    *(int2*)dst = o;
  } else {
    int e = (r >> 2) & 1;
    int mc = (r >> 3) * 4 + (r & 3);
    int kb = d0 >> 5, dq = (d0 >> 3) & 3;
    char* dst = k8 + (size_t)bh * NDH + chunk * 2048 + (e * 2 + kb) * 512 + mc * 32 + dq * 8;
    *(int2*)dst = o;
  }
}

// ---------------- flash causal attention: block-shared K/V in LDS -------
// R7 post-mortem: VALUBusy 53% vs ~15% hand-count -> libm exp2f/div
// overhead suspected. exp2f -> __builtin_amdgcn_exp2f (raw v_exp_f32;
// args <= 0 so FTZ is safe), 1/l -> v_rcp_f32.
__global__ __launch_bounds__(256) void k_flash(const char* __restrict__ q8,
                                               const char* __restrict__ k8,
                                               const _Float16* __restrict__ vh,
                                               const float* __restrict__ amax,
                                               _Float16* __restrict__ attn) {
  const int bh = blockIdx.x;
  const int tid = threadIdx.x;
  const int wave = tid >> 6, lane = tid & 63;
  const int mcol = lane & 15, quad = lane >> 4;
  const int g = 127 - (blockIdx.y * 4 + wave);      // this wave's q-group
  const int nt = (g >> 3) + 1;                      // its causal K-tile count
  const int ntmax = ((127 - blockIdx.y * 4) >> 3) + 1;  // block-max (wave 0)

  __shared__ __align__(16) char     Ks[8192];       // K fp8 tile (128 keys)
  __shared__ __align__(16) _Float16 Vs[8192];       // V fp16 tile (16KB)

  float sq = 448.f / fmaxf(amax[bh], 1e-12f);
  float sk = 448.f / fmaxf(amax[32 + bh], 1e-12f);
  const float c2 = (1.f / (sq * sk)) * 0.125f * 1.44269504089f;  // > 0

  const size_t pbase = (size_t)bh * NDH;
  const char* kpl = k8 + pbase;
  const _Float16* vpl = vh + pbase;
  const int qrow = g * 16 + mcol;
  long aq0, aq1;
  { const char* qp = q8 + pbase + (size_t)qrow * 64;
    aq0 = *(const long*)(qp + quad * 8); aq1 = *(const long*)(qp + 32 + quad * 8); }

  f32x4 O[4] = {};
  float m_i = -3e38f, l_i = 0.f;
  const int b = bh >> 4, h = bh & 15;
  const int kq = quad * 8;
  const int koff = mcol * 32 + quad * 8;
  const int voff = mcol * 32 + quad * 8;

#pragma unroll 1
  for (int t = 0; t < ntmax; ++t) {
    {
      const char* ks = kpl + (size_t)t * 8192;
      const _Float16* vs = vpl + (size_t)t * 8192;
#pragma unroll
      for (int r = 0; r < 2; ++r)
        GLOAD_LDS(ks + (tid + r * 256) * 16, &Ks[(tid + r * 256) * 16]);
#pragma unroll
      for (int r = 0; r < 4; ++r)
        GLOAD_LDS(vs + (tid + r * 256) * 8, &Vs[(tid + r * 256) * 8]);
    }
    __syncthreads();

    if (t < nt) {
      const int n0 = t * 128;
      f32x4 s[4][2];
#pragma unroll
      for (int p = 0; p < 4; ++p)
#pragma unroll
        for (int e = 0; e < 2; ++e) {
          long ka = *(const long*)&Ks[(p * 4 + e * 2 + 0) * 512 + koff];
          long kb = *(const long*)&Ks[(p * 4 + e * 2 + 1) * 512 + koff];
          f32x4 z = {};
          z = __builtin_amdgcn_mfma_f32_16x16x32_fp8_fp8(ka, aq0, z, 0, 0, 0);
          z = __builtin_amdgcn_mfma_f32_16x16x32_fp8_fp8(kb, aq1, z, 0, 0, 0);
          s[p][e] = z;
        }
      if (t >= nt - 1) {
#pragma unroll
        for (int p = 0; p < 4; ++p)
#pragma unroll
          for (int e = 0; e < 2; ++e)
#pragma unroll
            for (int r = 0; r < 4; ++r) {
              int key = n0 + p * 32 + kq + e * 4 + r;
              s[p][e][r] = (key <= qrow) ? s[p][e][r] : -3e38f;
            }
      }
      float fm[8];
#pragma unroll
      for (int p = 0; p < 4; ++p)
#pragma unroll
        for (int e = 0; e < 2; ++e) {
          f32x4 v = s[p][e];
          fm[p * 2 + e] = fmaxf(fmaxf(v[0], v[1]), fmaxf(v[2], v[3]));
        }
      float mx = fmaxf(fmaxf(fmaxf(fm[0], fm[1]), fmaxf(fm[2], fm[3])),
                       fmaxf(fmaxf(fm[4], fm[5]), fmaxf(fm[6], fm[7])));
      mx = fmaxf(mx, m_i);
      mx = fmaxf(mx, __shfl_xor(mx, 16));
      mx = fmaxf(mx, __shfl_xor(mx, 32));
      float alpha = __builtin_amdgcn_exp2f((m_i - mx) * c2);
      m_i = mx;
      const float nh = -mx * c2;
      float fs[8];
#pragma unroll
      for (int p = 0; p < 4; ++p)
#pragma unroll
        for (int e = 0; e < 2; ++e) {
          float p0 = __builtin_amdgcn_exp2f(fmaf(s[p][e][0], c2, nh));
          float p1 = __builtin_amdgcn_exp2f(fmaf(s[p][e][1], c2, nh));
          float p2 = __builtin_amdgcn_exp2f(fmaf(s[p][e][2], c2, nh));
          float p3 = __builtin_amdgcn_exp2f(fmaf(s[p][e][3], c2, nh));
          s[p][e][0] = p0; s[p][e][1] = p1; s[p][e][2] = p2; s[p][e][3] = p3;
          fs[p * 2 + e] = (p0 + p1) + (p2 + p3);
        }
      float sum = ((fs[0] + fs[1]) + (fs[2] + fs[3])) + ((fs[4] + fs[5]) + (fs[6] + fs[7]));
      sum += __shfl_xor(sum, 16);
      sum += __shfl_xor(sum, 32);
      l_i = l_i * alpha + sum;
#pragma unroll
      for (int dt = 0; dt < 4; ++dt)
#pragma unroll
        for (int r = 0; r < 4; ++r)
          O[dt][r] *= alpha;
#pragma unroll
      for (int p = 0; p < 4; ++p) {
        f16x8 pb;
        h16x2* pb2 = (h16x2*)&pb;
        pb2[0] = __builtin_amdgcn_cvt_pkrtz(s[p][0][0], s[p][0][1]);
        pb2[1] = __builtin_amdgcn_cvt_pkrtz(s[p][0][2], s[p][0][3]);
        pb2[2] = __builtin_amdgcn_cvt_pkrtz(s[p][1][0], s[p][1][1]);
        pb2[3] = __builtin_amdgcn_cvt_pkrtz(s[p][1][2], s[p][1][3]);
#pragma unroll
        for (int dt = 0; dt < 4; ++dt) {
          f16x8 va = *(const f16x8*)&Vs[p * 2048 + dt * 512 + voff];
          O[dt] = __builtin_amdgcn_mfma_f32_16x16x32_f16(va, pb, O[dt], 0, 0, 0);
        }
      }
    }
    __syncthreads();
  }

  float rl = __builtin_amdgcn_rcpf(l_i);
  _Float16* op = attn + ((size_t)b * 2048 + qrow) * 1024 + h * 64;
#pragma unroll
  for (int dt = 0; dt < 4; ++dt) {
    f16x4 o;
    o.x = (_Float16)(O[dt][0] * rl);
    o.y = (_Float16)(O[dt][1] * rl);
    o.z = (_Float16)(O[dt][2] * rl);
    o.w = (_Float16)(O[dt][3] * rl);
    *(f16x4*)(op + dt * 16 + quad * 4) = o;
  }
}

// ---------------- GEMM2: out = attn @ w_proj + b (BK=64 + swizzle) -------
__global__ __launch_bounds__(256) void k_gemm_out(const _Float16* __restrict__ A,
                                                  const _Float16* __restrict__ BT,
                                                  const float* __restrict__ bias,
                                                  float* __restrict__ out) {
  __shared__ __align__(16) _Float16 As[128 * 64];
  __shared__ __align__(16) _Float16 Bs[128 * 64];
  const int tid = threadIdx.x, lane = tid & 63, wave = tid >> 6;
  const int wm = wave >> 1, wn = wave & 1;
  const int mcol = lane & 15, quad = lane >> 4;
  const int m0 = blockIdx.x * 128, n0 = blockIdx.y * 128;
  const int swa = mcol & 7;
  f32x4 acc[4][4] = {};

#pragma unroll 1
  for (int k0 = 0; k0 < 1024; k0 += 64) {
#pragma unroll
    for (int r = 0; r < 4; ++r) {
      int s = tid + r * 256;
      int row = s >> 3, kc = (s & 7) ^ (row & 7);
      GLOAD_LDS(A  + (size_t)(m0 + row) * 1024 + k0 + kc * 8, &As[s * 8]);
      GLOAD_LDS(BT + (size_t)(n0 + row) * 1024 + k0 + kc * 8, &Bs[s * 8]);
    }
    __syncthreads();
#pragma unroll
    for (int kk = 0; kk < 2; ++kk) {
      f16x8 af[4], bf[4];
#pragma unroll
      for (int tm = 0; tm < 4; ++tm) {
        int row = wm * 64 + tm * 16 + mcol;
        af[tm] = *(const f16x8*)&As[(row * 8 + ((kk * 4 + quad) ^ swa)) * 8];
      }
#pragma unroll
      for (int tn = 0; tn < 4; ++tn) {
        int row = wn * 64 + tn * 16 + mcol;
        bf[tn] = *(const f16x8*)&Bs[(row * 8 + ((kk * 4 + quad) ^ swa)) * 8];
      }
#pragma unroll
      for (int tm = 0; tm < 4; ++tm)
#pragma unroll
        for (int tn = 0; tn < 4; ++tn)
          acc[tm][tn] = __builtin_amdgcn_mfma_f32_16x16x32_f16(af[tm], bf[tn], acc[tm][tn], 0, 0, 0);
    }
    __syncthreads();
  }

#pragma unroll
  for (int tm = 0; tm < 4; ++tm)
#pragma unroll
    for (int tn = 0; tn < 4; ++tn)
#pragma unroll
      for (int reg = 0; reg < 4; ++reg) {
        int row = m0 + wm * 64 + tm * 16 + quad * 4 + reg;
        int col = n0 + wn * 64 + tn * 16 + mcol;
        out[(size_t)row * 1024 + col] = acc[tm][tn][reg] + bias[col];
      }
}

extern "C" void kernel_launch(void* const* d_in, const int* in_sizes, int n_in,
                              void* d_out, int out_size, void* d_ws, size_t ws_size,
                              hipStream_t stream) {
  const float* x      = (const float*)d_in[0];
  const float* w_qkv  = (const float*)d_in[1];
  const float* w_proj = (const float*)d_in[2];
  const float* b_proj = (const float*)d_in[3];
  float* out = (float*)d_out;

  char* ws = (char*)d_ws;
  _Float16* xh   = (_Float16*)ws; ws += (size_t)M1 * C_ * 2;
  _Float16* whT  = (_Float16*)ws; ws += (size_t)3 * C_ * C_ * 2;
  _Float16* wpT  = (_Float16*)ws; ws += (size_t)C_ * C_ * 2;
  _Float16* qh   = (_Float16*)ws; ws += (size_t)BH_ * NDH * 2;
  _Float16* kh   = (_Float16*)ws; ws += (size_t)BH_ * NDH * 2;
  _Float16* vh   = (_Float16*)ws; ws += (size_t)BH_ * NDH * 2;
  char*     q8   = (char*)ws;     ws += (size_t)BH_ * NDH;
  char*     k8   = (char*)ws;     ws += (size_t)BH_ * NDH;
  _Float16* attn = (_Float16*)ws; ws += (size_t)M1 * C_ * 2;
  float*    amx  = (float*)ws;    ws += 256;

  k_prep<<<5120, 256, 0, stream>>>(x, xh, w_qkv, w_proj, whT, wpT, (unsigned*)amx);
  k_gemm_qkv<<<dim3(M1 / 128, 3 * C_ / 128), 256, 0, stream>>>(xh, whT, qh, kh, vh, (unsigned*)amx);
  k_quant<<<4096, 256, 0, stream>>>(qh, kh, amx, q8, k8);
  k_flash<<<dim3(32, 32), 256, 0, stream>>>(q8, k8, vh, amx, attn);
  k_gemm_out<<<dim3(M1 / 128, C_ / 128), 256, 0, stream>>>(attn, wpT, b_proj, out);
}

// Round 9
// 192.464 us; speedup vs baseline: 1.1111x; 1.0432x over previous
//
#include <hip/hip_runtime.h>

// Problem constants
#define B_   2
#define N_   2048
#define C_   1024
#define H_   16
#define D_   64
#define BH_  (B_*H_)      // 32
#define NDH  (N_*D_)      // 131072 elems per (b,h) plane
#define M1   (B_*N_)      // 4096 rows

typedef __attribute__((ext_vector_type(4))) float    f32x4;
typedef __attribute__((ext_vector_type(8))) _Float16 f16x8;
typedef __attribute__((ext_vector_type(4))) _Float16 f16x4;
typedef __attribute__((ext_vector_type(2))) __fp16   h16x2;

#define GLOAD_LDS(gp, lp) \
  __builtin_amdgcn_global_load_lds((const __attribute__((address_space(1))) void*)(gp), \
                                   (__attribute__((address_space(3))) void*)(lp), 16, 0, 0)

// ---- merged prep: fp32->fp16 convert of x (blocks 0..4095) +
//      fp32->fp16 transpose of w_qkv/w_proj + amax zero-init (4096..5119) ----
__global__ __launch_bounds__(256) void k_prep(const float* __restrict__ x,
                                              _Float16* __restrict__ xh,
                                              const float* __restrict__ wq,
                                              const float* __restrict__ wp,
                                              _Float16* __restrict__ whT,
                                              _Float16* __restrict__ wpT,
                                              unsigned* __restrict__ amax_u) {
  __shared__ _Float16 t[64][68];
  int bid = blockIdx.x;
  if (bid < 4096) {
    int i = bid * 256 + threadIdx.x;       // n4 = 4096*256 exactly
    float4 v = ((const float4*)x)[i];
    f16x4 o;
    o.x = (_Float16)v.x; o.y = (_Float16)v.y; o.z = (_Float16)v.z; o.w = (_Float16)v.w;
    ((f16x4*)xh)[i] = o;
    return;
  }
  int idx = bid - 4096;
  if (idx == 0 && threadIdx.x < 64) amax_u[threadIdx.x] = 0u;
  const float* in; _Float16* out; int Cc, cx, cy;
  if (idx < 768) { in = wq; out = whT; Cc = 3072; cx = idx % 48; cy = idx / 48; }
  else { idx -= 768; in = wp; out = wpT; Cc = 1024; cx = idx % 16; cy = idx / 16; }
  const int R = 1024;
  int c0 = cx * 64, r0 = cy * 64;
  int tid = threadIdx.x;
  int cq = tid & 15, rq = tid >> 4;
#pragma unroll
  for (int i = 0; i < 4; ++i) {
    int r = rq + i * 16;
    float4 v = *(const float4*)(in + (size_t)(r0 + r) * Cc + c0 + cq * 4);
    t[r][cq*4+0] = (_Float16)v.x;
    t[r][cq*4+1] = (_Float16)v.y;
    t[r][cq*4+2] = (_Float16)v.z;
    t[r][cq*4+3] = (_Float16)v.w;
  }
  __syncthreads();
#pragma unroll
  for (int i = 0; i < 4; ++i) {
    int c = rq + i * 16;
    f16x4 o;
    o.x = t[cq*4+0][c];
    o.y = t[cq*4+1][c];
    o.z = t[cq*4+2][c];
    o.w = t[cq*4+3][c];
    *(f16x4*)(out + (size_t)(c0 + c) * R + r0 + cq * 4) = o;
  }
}

// ---------------- GEMM1: qkv = x @ w_qkv -------------------------------
// BK=64, XOR swizzle (R7: conflicts -> 0) + R8: true async pipeline:
// double-buffered LDS with RAW s_barrier + counted "s_waitcnt vmcnt(8)"
// so the next tile's 8 global_load_lds stay in flight across the whole
// compute phase. (R6's __syncthreads dbuf failed because its implicit
// vmcnt(0) drained the prefetch at the barrier.)
__global__ __launch_bounds__(256) void k_gemm_qkv(const _Float16* __restrict__ A,
                                                  const _Float16* __restrict__ BT,
                                                  _Float16* __restrict__ qh,
                                                  _Float16* __restrict__ kh,
                                                  _Float16* __restrict__ vh,
                                                  unsigned* __restrict__ amax_u) {
  __shared__ __align__(16) _Float16 As[2][128 * 64];
  __shared__ __align__(16) _Float16 Bs[2][128 * 64];
  const int tid = threadIdx.x, lane = tid & 63, wave = tid >> 6;
  const int wm = wave >> 1, wn = wave & 1;
  const int mcol = lane & 15, quad = lane >> 4;
  const int m0 = blockIdx.x * 128, n0 = blockIdx.y * 128;
  const int swa = mcol & 7;
  f32x4 acc[4][4] = {};

  auto stage = [&](int buf, int k0) {           // 8 global_load_lds / thread
#pragma unroll
    for (int r = 0; r < 4; ++r) {
      int s = tid + r * 256;                    // LDS slot (16B), linear dest
      int row = s >> 3, kc = (s & 7) ^ (row & 7);  // pre-swizzled source
      GLOAD_LDS(A  + (size_t)(m0 + row) * 1024 + k0 + kc * 8, &As[buf][s * 8]);
      GLOAD_LDS(BT + (size_t)(n0 + row) * 1024 + k0 + kc * 8, &Bs[buf][s * 8]);
    }
  };
  auto compute = [&](int buf) {
#pragma unroll
    for (int kk = 0; kk < 2; ++kk) {
      f16x8 af[4], bf[4];
#pragma unroll
      for (int tm = 0; tm < 4; ++tm) {
        int row = wm * 64 + tm * 16 + mcol;
        af[tm] = *(const f16x8*)&As[buf][(row * 8 + ((kk * 4 + quad) ^ swa)) * 8];
      }
#pragma unroll
      for (int tn = 0; tn < 4; ++tn) {
        int row = wn * 64 + tn * 16 + mcol;
        bf[tn] = *(const f16x8*)&Bs[buf][(row * 8 + ((kk * 4 + quad) ^ swa)) * 8];
      }
#pragma unroll
      for (int tm = 0; tm < 4; ++tm)
#pragma unroll
        for (int tn = 0; tn < 4; ++tn)
          acc[tm][tn] = __builtin_amdgcn_mfma_f32_16x16x32_f16(af[tm], bf[tn], acc[tm][tn], 0, 0, 0);
    }
  };

  stage(0, 0);                                  // 8 loads outstanding
#pragma unroll 1
  for (int t = 0; t < 16; ++t) {
    const int cur = t & 1;
    __builtin_amdgcn_s_barrier();               // all waves done reading buf cur^1
    if (t + 1 < 16) {
      stage(cur ^ 1, (t + 1) * 64);             // overwrite safe; 16 outstanding
      asm volatile("s_waitcnt vmcnt(8)" ::: "memory");  // cur's 8 landed; next 8 in flight
    } else {
      asm volatile("s_waitcnt vmcnt(0)" ::: "memory");
    }
    __builtin_amdgcn_s_barrier();               // block-wide: cur fully staged
    __builtin_amdgcn_sched_barrier(0);
    compute(cur);
  }

  const int sec = n0 >> 10;
  if (sec < 2) {
    _Float16* dst = sec ? kh : qh;
    float mxv = 0.f;
#pragma unroll
    for (int tm = 0; tm < 4; ++tm)
#pragma unroll
      for (int tn = 0; tn < 4; ++tn) {
        int rowb = m0 + wm * 64 + tm * 16 + quad * 4;
        int col = n0 + wn * 64 + tn * 16 + mcol;
        int cc = col & 1023, h = cc >> 6, d = cc & 63;
        int b = rowb >> 11, n = rowb & 2047;
        f32x4 a = acc[tm][tn];
        mxv = fmaxf(mxv, fmaxf(fmaxf(fabsf(a[0]), fabsf(a[1])),
                               fmaxf(fabsf(a[2]), fabsf(a[3]))));
        f16x4 o;
        o.x = (_Float16)a[0]; o.y = (_Float16)a[1];
        o.z = (_Float16)a[2]; o.w = (_Float16)a[3];
        *(f16x4*)&dst[(size_t)(b * 16 + h) * 131072 + (size_t)(n >> 5) * 2048 + d * 32 + (n & 31)] = o;
      }
#pragma unroll
    for (int off = 32; off; off >>= 1) mxv = fmaxf(mxv, __shfl_xor(mxv, off));
    if (lane == 0) {
      int head = ((n0 & 1023) >> 6) + wn;
      int plane = (m0 >> 11) * 16 + head;
      atomicMax(&amax_u[sec * 32 + plane], __float_as_uint(mxv));
    }
  } else {
#pragma unroll
    for (int tm = 0; tm < 4; ++tm)
#pragma unroll
      for (int tn = 0; tn < 4; ++tn) {
        int rowb = m0 + wm * 64 + tm * 16 + quad * 4;
        int col = n0 + wn * 64 + tn * 16 + mcol;
        int cc = col & 1023, h = cc >> 6, d = cc & 63;
        int b = rowb >> 11, n = rowb & 2047;
        f16x4 o;
        o.x = (_Float16)acc[tm][tn][0];
        o.y = (_Float16)acc[tm][tn][1];
        o.z = (_Float16)acc[tm][tn][2];
        o.w = (_Float16)acc[tm][tn][3];
        *(f16x4*)&vh[(size_t)(b * 16 + h) * 131072 + (size_t)(n >> 5) * 2048 + d * 32 + (n & 31)] = o;
      }
  }
}

// ---------------- fp8 e4m3 quantize (tiled fp16 in, LDS transpose) -------
__global__ __launch_bounds__(256) void k_quant(const _Float16* __restrict__ qh,
                                               const _Float16* __restrict__ kh,
                                               const float* __restrict__ amax,
                                               char* __restrict__ q8,
                                               char* __restrict__ k8) {
  __shared__ ushort T[32][72];   // 144B rows: 16B-aligned reads
  int blk = blockIdx.x;
  int which = blk >> 11;
  int idx = blk & 2047;
  int bh = idx >> 6, chunk = idx & 63;
  const _Float16* src = (which ? kh : qh) + (size_t)bh * NDH + chunk * 2048;
  float s = 448.f / fmaxf(amax[which * 32 + bh], 1e-12f);
  int t = threadIdx.x;
  f16x8 v = *(const f16x8*)(src + t * 8);
  int d = t >> 2, kk0 = (t & 3) * 8;
#pragma unroll
  for (int j = 0; j < 8; ++j) T[kk0 + j][d] = ((const ushort*)&v)[j];
  __syncthreads();
  int r = t >> 3, d0 = (t & 7) * 8;
  f16x8 row = *(const f16x8*)&T[r][d0];
  float f[8];
#pragma unroll
  for (int j = 0; j < 8; ++j) f[j] = (float)((const _Float16*)&row)[j] * s;
  int lo = 0, hi = 0;
  lo = __builtin_amdgcn_cvt_pk_fp8_f32(f[0], f[1], lo, false);
  lo = __builtin_amdgcn_cvt_pk_fp8_f32(f[2], f[3], lo, true);
  hi = __builtin_amdgcn_cvt_pk_fp8_f32(f[4], f[5], hi, false);
  hi = __builtin_amdgcn_cvt_pk_fp8_f32(f[6], f[7], hi, true);
  int2 o; o.x = lo; o.y = hi;
  if (which == 0) {
    char* dst = q8 + (size_t)bh * NDH + (size_t)(chunk * 32 + r) * 64 + d0;
    *(int2*)dst = o;
  } else {
    int e = (r >> 2) & 1;
    int mc = (r >> 3) * 4 + (r & 3);
    int kb = d0 >> 5, dq = (d0 >> 3) & 3;
    char* dst = k8 + (size_t)bh * NDH + chunk * 2048 + (e * 2 + kb) * 512 + mc * 32 + dq * 8;
    *(int2*)dst = o;
  }
}

// ---------------- flash causal attention: block-shared K/V in LDS -------
__global__ __launch_bounds__(256) void k_flash(const char* __restrict__ q8,
                                               const char* __restrict__ k8,
                                               const _Float16* __restrict__ vh,
                                               const float* __restrict__ amax,
                                               _Float16* __restrict__ attn) {
  const int bh = blockIdx.x;
  const int tid = threadIdx.x;
  const int wave = tid >> 6, lane = tid & 63;
  const int mcol = lane & 15, quad = lane >> 4;
  const int g = 127 - (blockIdx.y * 4 + wave);      // this wave's q-group
  const int nt = (g >> 3) + 1;                      // its causal K-tile count
  const int ntmax = ((127 - blockIdx.y * 4) >> 3) + 1;  // block-max (wave 0)

  __shared__ __align__(16) char     Ks[8192];       // K fp8 tile (128 keys)
  __shared__ __align__(16) _Float16 Vs[8192];       // V fp16 tile (16KB)

  float sq = 448.f / fmaxf(amax[bh], 1e-12f);
  float sk = 448.f / fmaxf(amax[32 + bh], 1e-12f);
  const float c2 = (1.f / (sq * sk)) * 0.125f * 1.44269504089f;  // > 0

  const size_t pbase = (size_t)bh * NDH;
  const char* kpl = k8 + pbase;
  const _Float16* vpl = vh + pbase;
  const int qrow = g * 16 + mcol;
  long aq0, aq1;
  { const char* qp = q8 + pbase + (size_t)qrow * 64;
    aq0 = *(const long*)(qp + quad * 8); aq1 = *(const long*)(qp + 32 + quad * 8); }

  f32x4 O[4] = {};
  float m_i = -3e38f, l_i = 0.f;
  const int b = bh >> 4, h = bh & 15;
  const int kq = quad * 8;
  const int koff = mcol * 32 + quad * 8;
  const int voff = mcol * 32 + quad * 8;

#pragma unroll 1
  for (int t = 0; t < ntmax; ++t) {
    {
      const char* ks = kpl + (size_t)t * 8192;
      const _Float16* vs = vpl + (size_t)t * 8192;
#pragma unroll
      for (int r = 0; r < 2; ++r)
        GLOAD_LDS(ks + (tid + r * 256) * 16, &Ks[(tid + r * 256) * 16]);
#pragma unroll
      for (int r = 0; r < 4; ++r)
        GLOAD_LDS(vs + (tid + r * 256) * 8, &Vs[(tid + r * 256) * 8]);
    }
    __syncthreads();

    if (t < nt) {
      const int n0 = t * 128;
      f32x4 s[4][2];
#pragma unroll
      for (int p = 0; p < 4; ++p)
#pragma unroll
        for (int e = 0; e < 2; ++e) {
          long ka = *(const long*)&Ks[(p * 4 + e * 2 + 0) * 512 + koff];
          long kb = *(const long*)&Ks[(p * 4 + e * 2 + 1) * 512 + koff];
          f32x4 z = {};
          z = __builtin_amdgcn_mfma_f32_16x16x32_fp8_fp8(ka, aq0, z, 0, 0, 0);
          z = __builtin_amdgcn_mfma_f32_16x16x32_fp8_fp8(kb, aq1, z, 0, 0, 0);
          s[p][e] = z;
        }
      if (t >= nt - 1) {
#pragma unroll
        for (int p = 0; p < 4; ++p)
#pragma unroll
          for (int e = 0; e < 2; ++e)
#pragma unroll
            for (int r = 0; r < 4; ++r) {
              int key = n0 + p * 32 + kq + e * 4 + r;
              s[p][e][r] = (key <= qrow) ? s[p][e][r] : -3e38f;
            }
      }
      float fm[8];
#pragma unroll
      for (int p = 0; p < 4; ++p)
#pragma unroll
        for (int e = 0; e < 2; ++e) {
          f32x4 v = s[p][e];
          fm[p * 2 + e] = fmaxf(fmaxf(v[0], v[1]), fmaxf(v[2], v[3]));
        }
      float mx = fmaxf(fmaxf(fmaxf(fm[0], fm[1]), fmaxf(fm[2], fm[3])),
                       fmaxf(fmaxf(fm[4], fm[5]), fmaxf(fm[6], fm[7])));
      mx = fmaxf(mx, m_i);
      mx = fmaxf(mx, __shfl_xor(mx, 16));
      mx = fmaxf(mx, __shfl_xor(mx, 32));
      float alpha = __builtin_amdgcn_exp2f((m_i - mx) * c2);
      m_i = mx;
      const float nh = -mx * c2;
      float fs[8];
#pragma unroll
      for (int p = 0; p < 4; ++p)
#pragma unroll
        for (int e = 0; e < 2; ++e) {
          float p0 = __builtin_amdgcn_exp2f(fmaf(s[p][e][0], c2, nh));
          float p1 = __builtin_amdgcn_exp2f(fmaf(s[p][e][1], c2, nh));
          float p2 = __builtin_amdgcn_exp2f(fmaf(s[p][e][2], c2, nh));
          float p3 = __builtin_amdgcn_exp2f(fmaf(s[p][e][3], c2, nh));
          s[p][e][0] = p0; s[p][e][1] = p1; s[p][e][2] = p2; s[p][e][3] = p3;
          fs[p * 2 + e] = (p0 + p1) + (p2 + p3);
        }
      float sum = ((fs[0] + fs[1]) + (fs[2] + fs[3])) + ((fs[4] + fs[5]) + (fs[6] + fs[7]));
      sum += __shfl_xor(sum, 16);
      sum += __shfl_xor(sum, 32);
      l_i = l_i * alpha + sum;
#pragma unroll
      for (int dt = 0; dt < 4; ++dt)
#pragma unroll
        for (int r = 0; r < 4; ++r)
          O[dt][r] *= alpha;
#pragma unroll
      for (int p = 0; p < 4; ++p) {
        f16x8 pb;
        h16x2* pb2 = (h16x2*)&pb;
        pb2[0] = __builtin_amdgcn_cvt_pkrtz(s[p][0][0], s[p][0][1]);
        pb2[1] = __builtin_amdgcn_cvt_pkrtz(s[p][0][2], s[p][0][3]);
        pb2[2] = __builtin_amdgcn_cvt_pkrtz(s[p][1][0], s[p][1][1]);
        pb2[3] = __builtin_amdgcn_cvt_pkrtz(s[p][1][2], s[p][1][3]);
#pragma unroll
        for (int dt = 0; dt < 4; ++dt) {
          f16x8 va = *(const f16x8*)&Vs[p * 2048 + dt * 512 + voff];
          O[dt] = __builtin_amdgcn_mfma_f32_16x16x32_f16(va, pb, O[dt], 0, 0, 0);
        }
      }
    }
    __syncthreads();
  }

  float rl = __builtin_amdgcn_rcpf(l_i);
  _Float16* op = attn + ((size_t)b * 2048 + qrow) * 1024 + h * 64;
#pragma unroll
  for (int dt = 0; dt < 4; ++dt) {
    f16x4 o;
    o.x = (_Float16)(O[dt][0] * rl);
    o.y = (_Float16)(O[dt][1] * rl);
    o.z = (_Float16)(O[dt][2] * rl);
    o.w = (_Float16)(O[dt][3] * rl);
    *(f16x4*)(op + dt * 16 + quad * 4) = o;
  }
}

// ---------------- GEMM2: out = attn @ w_proj + b (same async pipeline) ---
__global__ __launch_bounds__(256) void k_gemm_out(const _Float16* __restrict__ A,
                                                  const _Float16* __restrict__ BT,
                                                  const float* __restrict__ bias,
                                                  float* __restrict__ out) {
  __shared__ __align__(16) _Float16 As[2][128 * 64];
  __shared__ __align__(16) _Float16 Bs[2][128 * 64];
  const int tid = threadIdx.x, lane = tid & 63, wave = tid >> 6;
  const int wm = wave >> 1, wn = wave & 1;
  const int mcol = lane & 15, quad = lane >> 4;
  const int m0 = blockIdx.x * 128, n0 = blockIdx.y * 128;
  const int swa = mcol & 7;
  f32x4 acc[4][4] = {};

  auto stage = [&](int buf, int k0) {
#pragma unroll
    for (int r = 0; r < 4; ++r) {
      int s = tid + r * 256;
      int row = s >> 3, kc = (s & 7) ^ (row & 7);
      GLOAD_LDS(A  + (size_t)(m0 + row) * 1024 + k0 + kc * 8, &As[buf][s * 8]);
      GLOAD_LDS(BT + (size_t)(n0 + row) * 1024 + k0 + kc * 8, &Bs[buf][s * 8]);
    }
  };
  auto compute = [&](int buf) {
#pragma unroll
    for (int kk = 0; kk < 2; ++kk) {
      f16x8 af[4], bf[4];
#pragma unroll
      for (int tm = 0; tm < 4; ++tm) {
        int row = wm * 64 + tm * 16 + mcol;
        af[tm] = *(const f16x8*)&As[buf][(row * 8 + ((kk * 4 + quad) ^ swa)) * 8];
      }
#pragma unroll
      for (int tn = 0; tn < 4; ++tn) {
        int row = wn * 64 + tn * 16 + mcol;
        bf[tn] = *(const f16x8*)&Bs[buf][(row * 8 + ((kk * 4 + quad) ^ swa)) * 8];
      }
#pragma unroll
      for (int tm = 0; tm < 4; ++tm)
#pragma unroll
        for (int tn = 0; tn < 4; ++tn)
          acc[tm][tn] = __builtin_amdgcn_mfma_f32_16x16x32_f16(af[tm], bf[tn], acc[tm][tn], 0, 0, 0);
    }
  };

  stage(0, 0);
#pragma unroll 1
  for (int t = 0; t < 16; ++t) {
    const int cur = t & 1;
    __builtin_amdgcn_s_barrier();
    if (t + 1 < 16) {
      stage(cur ^ 1, (t + 1) * 64);
      asm volatile("s_waitcnt vmcnt(8)" ::: "memory");
    } else {
      asm volatile("s_waitcnt vmcnt(0)" ::: "memory");
    }
    __builtin_amdgcn_s_barrier();
    __builtin_amdgcn_sched_barrier(0);
    compute(cur);
  }

#pragma unroll
  for (int tm = 0; tm < 4; ++tm)
#pragma unroll
    for (int tn = 0; tn < 4; ++tn)
#pragma unroll
      for (int reg = 0; reg < 4; ++reg) {
        int row = m0 + wm * 64 + tm * 16 + quad * 4 + reg;
        int col = n0 + wn * 64 + tn * 16 + mcol;
        out[(size_t)row * 1024 + col] = acc[tm][tn][reg] + bias[col];
      }
}

extern "C" void kernel_launch(void* const* d_in, const int* in_sizes, int n_in,
                              void* d_out, int out_size, void* d_ws, size_t ws_size,
                              hipStream_t stream) {
  const float* x      = (const float*)d_in[0];
  const float* w_qkv  = (const float*)d_in[1];
  const float* w_proj = (const float*)d_in[2];
  const float* b_proj = (const float*)d_in[3];
  float* out = (float*)d_out;

  char* ws = (char*)d_ws;
  _Float16* xh   = (_Float16*)ws; ws += (size_t)M1 * C_ * 2;
  _Float16* whT  = (_Float16*)ws; ws += (size_t)3 * C_ * C_ * 2;
  _Float16* wpT  = (_Float16*)ws; ws += (size_t)C_ * C_ * 2;
  _Float16* qh   = (_Float16*)ws; ws += (size_t)BH_ * NDH * 2;
  _Float16* kh   = (_Float16*)ws; ws += (size_t)BH_ * NDH * 2;
  _Float16* vh   = (_Float16*)ws; ws += (size_t)BH_ * NDH * 2;
  char*     q8   = (char*)ws;     ws += (size_t)BH_ * NDH;
  char*     k8   = (char*)ws;     ws += (size_t)BH_ * NDH;
  _Float16* attn = (_Float16*)ws; ws += (size_t)M1 * C_ * 2;
  float*    amx  = (float*)ws;    ws += 256;

  k_prep<<<5120, 256, 0, stream>>>(x, xh, w_qkv, w_proj, whT, wpT, (unsigned*)amx);
  k_gemm_qkv<<<dim3(M1 / 128, 3 * C_ / 128), 256, 0, stream>>>(xh, whT, qh, kh, vh, (unsigned*)amx);
  k_quant<<<4096, 256, 0, stream>>>(qh, kh, amx, q8, k8);
  k_flash<<<dim3(32, 32), 256, 0, stream>>>(q8, k8, vh, amx, attn);
  k_gemm_out<<<dim3(M1 / 128, C_ / 128), 256, 0, stream>>>(attn, wpT, b_proj, out);
}

// Round 10
// 183.808 us; speedup vs baseline: 1.1634x; 1.0471x over previous
//
#include <hip/hip_runtime.h>

// Problem constants
#define B_   2
#define N_   2048
#define C_   1024
#define H_   16
#define D_   64
#define BH_  (B_*H_)      // 32
#define NDH  (N_*D_)      // 131072 elems per (b,h) plane
#define M1   (B_*N_)      // 4096 rows

typedef __attribute__((ext_vector_type(4))) float    f32x4;
typedef __attribute__((ext_vector_type(8))) _Float16 f16x8;
typedef __attribute__((ext_vector_type(4))) _Float16 f16x4;
typedef __attribute__((ext_vector_type(2))) __fp16   h16x2;

#define GLOAD_LDS(gp, lp) \
  __builtin_amdgcn_global_load_lds((const __attribute__((address_space(1))) void*)(gp), \
                                   (__attribute__((address_space(3))) void*)(lp), 16, 0, 0)

// ---- merged prep: fp32->fp16 convert of x (blocks 0..4095) +
//      fp32->fp16 transpose of w_qkv/w_proj + amax zero-init (4096..5119) ----
__global__ __launch_bounds__(256) void k_prep(const float* __restrict__ x,
                                              _Float16* __restrict__ xh,
                                              const float* __restrict__ wq,
                                              const float* __restrict__ wp,
                                              _Float16* __restrict__ whT,
                                              _Float16* __restrict__ wpT,
                                              unsigned* __restrict__ amax_u) {
  __shared__ _Float16 t[64][68];
  int bid = blockIdx.x;
  if (bid < 4096) {
    int i = bid * 256 + threadIdx.x;       // n4 = 4096*256 exactly
    float4 v = ((const float4*)x)[i];
    f16x4 o;
    o.x = (_Float16)v.x; o.y = (_Float16)v.y; o.z = (_Float16)v.z; o.w = (_Float16)v.w;
    ((f16x4*)xh)[i] = o;
    return;
  }
  int idx = bid - 4096;
  if (idx == 0 && threadIdx.x < 64) amax_u[threadIdx.x] = 0u;
  const float* in; _Float16* out; int Cc, cx, cy;
  if (idx < 768) { in = wq; out = whT; Cc = 3072; cx = idx % 48; cy = idx / 48; }
  else { idx -= 768; in = wp; out = wpT; Cc = 1024; cx = idx % 16; cy = idx / 16; }
  const int R = 1024;
  int c0 = cx * 64, r0 = cy * 64;
  int tid = threadIdx.x;
  int cq = tid & 15, rq = tid >> 4;
#pragma unroll
  for (int i = 0; i < 4; ++i) {
    int r = rq + i * 16;
    float4 v = *(const float4*)(in + (size_t)(r0 + r) * Cc + c0 + cq * 4);
    t[r][cq*4+0] = (_Float16)v.x;
    t[r][cq*4+1] = (_Float16)v.y;
    t[r][cq*4+2] = (_Float16)v.z;
    t[r][cq*4+3] = (_Float16)v.w;
  }
  __syncthreads();
#pragma unroll
  for (int i = 0; i < 4; ++i) {
    int c = rq + i * 16;
    f16x4 o;
    o.x = t[cq*4+0][c];
    o.y = t[cq*4+1][c];
    o.z = t[cq*4+2][c];
    o.w = t[cq*4+3][c];
    *(f16x4*)(out + (size_t)(c0 + c) * R + r0 + cq * 4) = o;
  }
}

// ---------------- GEMM1: qkv = x @ w_qkv -------------------------------
// BK=64, XOR swizzle (R7) + counted-vmcnt async dbuf (R8).
// R9: V written in quarter-wave-conflict-free fragment layout
// (elem within 512-slab: quad*128 + mcol*8 instead of mcol*32 + quad*8).
__global__ __launch_bounds__(256) void k_gemm_qkv(const _Float16* __restrict__ A,
                                                  const _Float16* __restrict__ BT,
                                                  _Float16* __restrict__ qh,
                                                  _Float16* __restrict__ kh,
                                                  _Float16* __restrict__ vh,
                                                  unsigned* __restrict__ amax_u) {
  __shared__ __align__(16) _Float16 As[2][128 * 64];
  __shared__ __align__(16) _Float16 Bs[2][128 * 64];
  const int tid = threadIdx.x, lane = tid & 63, wave = tid >> 6;
  const int wm = wave >> 1, wn = wave & 1;
  const int mcol = lane & 15, quad = lane >> 4;
  const int m0 = blockIdx.x * 128, n0 = blockIdx.y * 128;
  const int swa = mcol & 7;
  f32x4 acc[4][4] = {};

  auto stage = [&](int buf, int k0) {           // 8 global_load_lds / thread
#pragma unroll
    for (int r = 0; r < 4; ++r) {
      int s = tid + r * 256;                    // LDS slot (16B), linear dest
      int row = s >> 3, kc = (s & 7) ^ (row & 7);  // pre-swizzled source
      GLOAD_LDS(A  + (size_t)(m0 + row) * 1024 + k0 + kc * 8, &As[buf][s * 8]);
      GLOAD_LDS(BT + (size_t)(n0 + row) * 1024 + k0 + kc * 8, &Bs[buf][s * 8]);
    }
  };
  auto compute = [&](int buf) {
#pragma unroll
    for (int kk = 0; kk < 2; ++kk) {
      f16x8 af[4], bf[4];
#pragma unroll
      for (int tm = 0; tm < 4; ++tm) {
        int row = wm * 64 + tm * 16 + mcol;
        af[tm] = *(const f16x8*)&As[buf][(row * 8 + ((kk * 4 + quad) ^ swa)) * 8];
      }
#pragma unroll
      for (int tn = 0; tn < 4; ++tn) {
        int row = wn * 64 + tn * 16 + mcol;
        bf[tn] = *(const f16x8*)&Bs[buf][(row * 8 + ((kk * 4 + quad) ^ swa)) * 8];
      }
#pragma unroll
      for (int tm = 0; tm < 4; ++tm)
#pragma unroll
        for (int tn = 0; tn < 4; ++tn)
          acc[tm][tn] = __builtin_amdgcn_mfma_f32_16x16x32_f16(af[tm], bf[tn], acc[tm][tn], 0, 0, 0);
    }
  };

  stage(0, 0);
#pragma unroll 1
  for (int t = 0; t < 16; ++t) {
    const int cur = t & 1;
    __builtin_amdgcn_s_barrier();
    if (t + 1 < 16) {
      stage(cur ^ 1, (t + 1) * 64);
      asm volatile("s_waitcnt vmcnt(8)" ::: "memory");
    } else {
      asm volatile("s_waitcnt vmcnt(0)" ::: "memory");
    }
    __builtin_amdgcn_s_barrier();
    __builtin_amdgcn_sched_barrier(0);
    compute(cur);
  }

  const int sec = n0 >> 10;
  if (sec < 2) {
    _Float16* dst = sec ? kh : qh;
    float mxv = 0.f;
#pragma unroll
    for (int tm = 0; tm < 4; ++tm)
#pragma unroll
      for (int tn = 0; tn < 4; ++tn) {
        int rowb = m0 + wm * 64 + tm * 16 + quad * 4;
        int col = n0 + wn * 64 + tn * 16 + mcol;
        int cc = col & 1023, h = cc >> 6, d = cc & 63;
        int b = rowb >> 11, n = rowb & 2047;
        f32x4 a = acc[tm][tn];
        mxv = fmaxf(mxv, fmaxf(fmaxf(fabsf(a[0]), fabsf(a[1])),
                               fmaxf(fabsf(a[2]), fabsf(a[3]))));
        f16x4 o;
        o.x = (_Float16)a[0]; o.y = (_Float16)a[1];
        o.z = (_Float16)a[2]; o.w = (_Float16)a[3];
        *(f16x4*)&dst[(size_t)(b * 16 + h) * 131072 + (size_t)(n >> 5) * 2048 + d * 32 + (n & 31)] = o;
      }
#pragma unroll
    for (int off = 32; off; off >>= 1) mxv = fmaxf(mxv, __shfl_xor(mxv, off));
    if (lane == 0) {
      int head = ((n0 & 1023) >> 6) + wn;
      int plane = (m0 >> 11) * 16 + head;
      atomicMax(&amax_u[sec * 32 + plane], __float_as_uint(mxv));
    }
  } else {
    // V: fragment-transposed layout (R9): within each (n>>5) group of 2048
    // elems, slab (d>>4)*512, elem ((n>>3)&3)*128 + (d&15)*8 + (n&7).
#pragma unroll
    for (int tm = 0; tm < 4; ++tm)
#pragma unroll
      for (int tn = 0; tn < 4; ++tn) {
        int rowb = m0 + wm * 64 + tm * 16 + quad * 4;
        int col = n0 + wn * 64 + tn * 16 + mcol;
        int cc = col & 1023, h = cc >> 6, d = cc & 63;
        int b = rowb >> 11, n = rowb & 2047;
        f16x4 o;
        o.x = (_Float16)acc[tm][tn][0];
        o.y = (_Float16)acc[tm][tn][1];
        o.z = (_Float16)acc[tm][tn][2];
        o.w = (_Float16)acc[tm][tn][3];
        size_t e = (size_t)(b * 16 + h) * 131072 + (size_t)(n >> 5) * 2048
                 + (d >> 4) * 512 + ((n >> 3) & 3) * 128 + (d & 15) * 8 + (n & 7);
        *(f16x4*)&vh[e] = o;
      }
  }
}

// ---------------- fp8 e4m3 quantize (tiled fp16 in, LDS transpose) -------
// R9: K fragment interior relabeled to quad*128 + mcol*8 (conflict-free
// quarter-wave ds_read_b64 in flash). q8 unchanged.
__global__ __launch_bounds__(256) void k_quant(const _Float16* __restrict__ qh,
                                               const _Float16* __restrict__ kh,
                                               const float* __restrict__ amax,
                                               char* __restrict__ q8,
                                               char* __restrict__ k8) {
  __shared__ ushort T[32][72];   // 144B rows: 16B-aligned reads
  int blk = blockIdx.x;
  int which = blk >> 11;
  int idx = blk & 2047;
  int bh = idx >> 6, chunk = idx & 63;
  const _Float16* src = (which ? kh : qh) + (size_t)bh * NDH + chunk * 2048;
  float s = 448.f / fmaxf(amax[which * 32 + bh], 1e-12f);
  int t = threadIdx.x;
  f16x8 v = *(const f16x8*)(src + t * 8);
  int d = t >> 2, kk0 = (t & 3) * 8;
#pragma unroll
  for (int j = 0; j < 8; ++j) T[kk0 + j][d] = ((const ushort*)&v)[j];
  __syncthreads();
  int r = t >> 3, d0 = (t & 7) * 8;
  f16x8 row = *(const f16x8*)&T[r][d0];
  float f[8];
#pragma unroll
  for (int j = 0; j < 8; ++j) f[j] = (float)((const _Float16*)&row)[j] * s;
  int lo = 0, hi = 0;
  lo = __builtin_amdgcn_cvt_pk_fp8_f32(f[0], f[1], lo, false);
  lo = __builtin_amdgcn_cvt_pk_fp8_f32(f[2], f[3], lo, true);
  hi = __builtin_amdgcn_cvt_pk_fp8_f32(f[4], f[5], hi, false);
  hi = __builtin_amdgcn_cvt_pk_fp8_f32(f[6], f[7], hi, true);
  int2 o; o.x = lo; o.y = hi;
  if (which == 0) {
    char* dst = q8 + (size_t)bh * NDH + (size_t)(chunk * 32 + r) * 64 + d0;
    *(int2*)dst = o;
  } else {
    int e = (r >> 2) & 1;
    int mc = (r >> 3) * 4 + (r & 3);
    int kb = d0 >> 5, dq = (d0 >> 3) & 3;
    char* dst = k8 + (size_t)bh * NDH + chunk * 2048 + (e * 2 + kb) * 512 + dq * 128 + mc * 8;
    *(int2*)dst = o;
  }
}

// ---------------- flash causal attention: block-shared K/V in LDS -------
// R9: fragment interiors transposed (writers changed to match) so the
// quarter-wave bank pattern is conflict-free: K b64 at quad*128+mcol*8,
// V b128 at (elems) quad*128+mcol*8.
__global__ __launch_bounds__(256) void k_flash(const char* __restrict__ q8,
                                               const char* __restrict__ k8,
                                               const _Float16* __restrict__ vh,
                                               const float* __restrict__ amax,
                                               _Float16* __restrict__ attn) {
  const int bh = blockIdx.x;
  const int tid = threadIdx.x;
  const int wave = tid >> 6, lane = tid & 63;
  const int mcol = lane & 15, quad = lane >> 4;
  const int g = 127 - (blockIdx.y * 4 + wave);      // this wave's q-group
  const int nt = (g >> 3) + 1;                      // its causal K-tile count
  const int ntmax = ((127 - blockIdx.y * 4) >> 3) + 1;  // block-max (wave 0)

  __shared__ __align__(16) char     Ks[8192];       // K fp8 tile (128 keys)
  __shared__ __align__(16) _Float16 Vs[8192];       // V fp16 tile (16KB)

  float sq = 448.f / fmaxf(amax[bh], 1e-12f);
  float sk = 448.f / fmaxf(amax[32 + bh], 1e-12f);
  const float c2 = (1.f / (sq * sk)) * 0.125f * 1.44269504089f;  // > 0

  const size_t pbase = (size_t)bh * NDH;
  const char* kpl = k8 + pbase;
  const _Float16* vpl = vh + pbase;
  const int qrow = g * 16 + mcol;
  long aq0, aq1;
  { const char* qp = q8 + pbase + (size_t)qrow * 64;
    aq0 = *(const long*)(qp + quad * 8); aq1 = *(const long*)(qp + 32 + quad * 8); }

  f32x4 O[4] = {};
  float m_i = -3e38f, l_i = 0.f;
  const int b = bh >> 4, h = bh & 15;
  const int kq = quad * 8;
  const int koff = quad * 128 + mcol * 8;           // bytes into K fragment
  const int voff = quad * 128 + mcol * 8;           // elems into V slab

#pragma unroll 1
  for (int t = 0; t < ntmax; ++t) {
    {
      const char* ks = kpl + (size_t)t * 8192;
      const _Float16* vs = vpl + (size_t)t * 8192;
#pragma unroll
      for (int r = 0; r < 2; ++r)
        GLOAD_LDS(ks + (tid + r * 256) * 16, &Ks[(tid + r * 256) * 16]);
#pragma unroll
      for (int r = 0; r < 4; ++r)
        GLOAD_LDS(vs + (tid + r * 256) * 8, &Vs[(tid + r * 256) * 8]);
    }
    __syncthreads();

    if (t < nt) {
      const int n0 = t * 128;
      f32x4 s[4][2];
#pragma unroll
      for (int p = 0; p < 4; ++p)
#pragma unroll
        for (int e = 0; e < 2; ++e) {
          long ka = *(const long*)&Ks[(p * 4 + e * 2 + 0) * 512 + koff];
          long kb = *(const long*)&Ks[(p * 4 + e * 2 + 1) * 512 + koff];
          f32x4 z = {};
          z = __builtin_amdgcn_mfma_f32_16x16x32_fp8_fp8(ka, aq0, z, 0, 0, 0);
          z = __builtin_amdgcn_mfma_f32_16x16x32_fp8_fp8(kb, aq1, z, 0, 0, 0);
          s[p][e] = z;
        }
      if (t >= nt - 1) {
#pragma unroll
        for (int p = 0; p < 4; ++p)
#pragma unroll
          for (int e = 0; e < 2; ++e)
#pragma unroll
            for (int r = 0; r < 4; ++r) {
              int key = n0 + p * 32 + kq + e * 4 + r;
              s[p][e][r] = (key <= qrow) ? s[p][e][r] : -3e38f;
            }
      }
      float fm[8];
#pragma unroll
      for (int p = 0; p < 4; ++p)
#pragma unroll
        for (int e = 0; e < 2; ++e) {
          f32x4 v = s[p][e];
          fm[p * 2 + e] = fmaxf(fmaxf(v[0], v[1]), fmaxf(v[2], v[3]));
        }
      float mx = fmaxf(fmaxf(fmaxf(fm[0], fm[1]), fmaxf(fm[2], fm[3])),
                       fmaxf(fmaxf(fm[4], fm[5]), fmaxf(fm[6], fm[7])));
      mx = fmaxf(mx, m_i);
      mx = fmaxf(mx, __shfl_xor(mx, 16));
      mx = fmaxf(mx, __shfl_xor(mx, 32));
      float alpha = __builtin_amdgcn_exp2f((m_i - mx) * c2);
      m_i = mx;
      const float nh = -mx * c2;
      float fs[8];
#pragma unroll
      for (int p = 0; p < 4; ++p)
#pragma unroll
        for (int e = 0; e < 2; ++e) {
          float p0 = __builtin_amdgcn_exp2f(fmaf(s[p][e][0], c2, nh));
          float p1 = __builtin_amdgcn_exp2f(fmaf(s[p][e][1], c2, nh));
          float p2 = __builtin_amdgcn_exp2f(fmaf(s[p][e][2], c2, nh));
          float p3 = __builtin_amdgcn_exp2f(fmaf(s[p][e][3], c2, nh));
          s[p][e][0] = p0; s[p][e][1] = p1; s[p][e][2] = p2; s[p][e][3] = p3;
          fs[p * 2 + e] = (p0 + p1) + (p2 + p3);
        }
      float sum = ((fs[0] + fs[1]) + (fs[2] + fs[3])) + ((fs[4] + fs[5]) + (fs[6] + fs[7]));
      sum += __shfl_xor(sum, 16);
      sum += __shfl_xor(sum, 32);
      l_i = l_i * alpha + sum;
#pragma unroll
      for (int dt = 0; dt < 4; ++dt)
#pragma unroll
        for (int r = 0; r < 4; ++r)
          O[dt][r] *= alpha;
#pragma unroll
      for (int p = 0; p < 4; ++p) {
        f16x8 pb;
        h16x2* pb2 = (h16x2*)&pb;
        pb2[0] = __builtin_amdgcn_cvt_pkrtz(s[p][0][0], s[p][0][1]);
        pb2[1] = __builtin_amdgcn_cvt_pkrtz(s[p][0][2], s[p][0][3]);
        pb2[2] = __builtin_amdgcn_cvt_pkrtz(s[p][1][0], s[p][1][1]);
        pb2[3] = __builtin_amdgcn_cvt_pkrtz(s[p][1][2], s[p][1][3]);
#pragma unroll
        for (int dt = 0; dt < 4; ++dt) {
          f16x8 va = *(const f16x8*)&Vs[p * 2048 + dt * 512 + voff];
          O[dt] = __builtin_amdgcn_mfma_f32_16x16x32_f16(va, pb, O[dt], 0, 0, 0);
        }
      }
    }
    __syncthreads();
  }

  float rl = __builtin_amdgcn_rcpf(l_i);
  _Float16* op = attn + ((size_t)b * 2048 + qrow) * 1024 + h * 64;
#pragma unroll
  for (int dt = 0; dt < 4; ++dt) {
    f16x4 o;
    o.x = (_Float16)(O[dt][0] * rl);
    o.y = (_Float16)(O[dt][1] * rl);
    o.z = (_Float16)(O[dt][2] * rl);
    o.w = (_Float16)(O[dt][3] * rl);
    *(f16x4*)(op + dt * 16 + quad * 4) = o;
  }
}

// ---------------- GEMM2: out = attn @ w_proj + b (async pipeline) --------
__global__ __launch_bounds__(256) void k_gemm_out(const _Float16* __restrict__ A,
                                                  const _Float16* __restrict__ BT,
                                                  const float* __restrict__ bias,
                                                  float* __restrict__ out) {
  __shared__ __align__(16) _Float16 As[2][128 * 64];
  __shared__ __align__(16) _Float16 Bs[2][128 * 64];
  const int tid = threadIdx.x, lane = tid & 63, wave = tid >> 6;
  const int wm = wave >> 1, wn = wave & 1;
  const int mcol = lane & 15, quad = lane >> 4;
  const int m0 = blockIdx.x * 128, n0 = blockIdx.y * 128;
  const int swa = mcol & 7;
  f32x4 acc[4][4] = {};

  auto stage = [&](int buf, int k0) {
#pragma unroll
    for (int r = 0; r < 4; ++r) {
      int s = tid + r * 256;
      int row = s >> 3, kc = (s & 7) ^ (row & 7);
      GLOAD_LDS(A  + (size_t)(m0 + row) * 1024 + k0 + kc * 8, &As[buf][s * 8]);
      GLOAD_LDS(BT + (size_t)(n0 + row) * 1024 + k0 + kc * 8, &Bs[buf][s * 8]);
    }
  };
  auto compute = [&](int buf) {
#pragma unroll
    for (int kk = 0; kk < 2; ++kk) {
      f16x8 af[4], bf[4];
#pragma unroll
      for (int tm = 0; tm < 4; ++tm) {
        int row = wm * 64 + tm * 16 + mcol;
        af[tm] = *(const f16x8*)&As[buf][(row * 8 + ((kk * 4 + quad) ^ swa)) * 8];
      }
#pragma unroll
      for (int tn = 0; tn < 4; ++tn) {
        int row = wn * 64 + tn * 16 + mcol;
        bf[tn] = *(const f16x8*)&Bs[buf][(row * 8 + ((kk * 4 + quad) ^ swa)) * 8];
      }
#pragma unroll
      for (int tm = 0; tm < 4; ++tm)
#pragma unroll
        for (int tn = 0; tn < 4; ++tn)
          acc[tm][tn] = __builtin_amdgcn_mfma_f32_16x16x32_f16(af[tm], bf[tn], acc[tm][tn], 0, 0, 0);
    }
  };

  stage(0, 0);
#pragma unroll 1
  for (int t = 0; t < 16; ++t) {
    const int cur = t & 1;
    __builtin_amdgcn_s_barrier();
    if (t + 1 < 16) {
      stage(cur ^ 1, (t + 1) * 64);
      asm volatile("s_waitcnt vmcnt(8)" ::: "memory");
    } else {
      asm volatile("s_waitcnt vmcnt(0)" ::: "memory");
    }
    __builtin_amdgcn_s_barrier();
    __builtin_amdgcn_sched_barrier(0);
    compute(cur);
  }

#pragma unroll
  for (int tm = 0; tm < 4; ++tm)
#pragma unroll
    for (int tn = 0; tn < 4; ++tn)
#pragma unroll
      for (int reg = 0; reg < 4; ++reg) {
        int row = m0 + wm * 64 + tm * 16 + quad * 4 + reg;
        int col = n0 + wn * 64 + tn * 16 + mcol;
        out[(size_t)row * 1024 + col] = acc[tm][tn][reg] + bias[col];
      }
}

extern "C" void kernel_launch(void* const* d_in, const int* in_sizes, int n_in,
                              void* d_out, int out_size, void* d_ws, size_t ws_size,
                              hipStream_t stream) {
  const float* x      = (const float*)d_in[0];
  const float* w_qkv  = (const float*)d_in[1];
  const float* w_proj = (const float*)d_in[2];
  const float* b_proj = (const float*)d_in[3];
  float* out = (float*)d_out;

  char* ws = (char*)d_ws;
  _Float16* xh   = (_Float16*)ws; ws += (size_t)M1 * C_ * 2;
  _Float16* whT  = (_Float16*)ws; ws += (size_t)3 * C_ * C_ * 2;
  _Float16* wpT  = (_Float16*)ws; ws += (size_t)C_ * C_ * 2;
  _Float16* qh   = (_Float16*)ws; ws += (size_t)BH_ * NDH * 2;
  _Float16* kh   = (_Float16*)ws; ws += (size_t)BH_ * NDH * 2;
  _Float16* vh   = (_Float16*)ws; ws += (size_t)BH_ * NDH * 2;
  char*     q8   = (char*)ws;     ws += (size_t)BH_ * NDH;
  char*     k8   = (char*)ws;     ws += (size_t)BH_ * NDH;
  _Float16* attn = (_Float16*)ws; ws += (size_t)M1 * C_ * 2;
  float*    amx  = (float*)ws;    ws += 256;

  k_prep<<<5120, 256, 0, stream>>>(x, xh, w_qkv, w_proj, whT, wpT, (unsigned*)amx);
  k_gemm_qkv<<<dim3(M1 / 128, 3 * C_ / 128), 256, 0, stream>>>(xh, whT, qh, kh, vh, (unsigned*)amx);
  k_quant<<<4096, 256, 0, stream>>>(qh, kh, amx, q8, k8);
  k_flash<<<dim3(32, 32), 256, 0, stream>>>(q8, k8, vh, amx, attn);
  k_gemm_out<<<dim3(M1 / 128, C_ / 128), 256, 0, stream>>>(attn, wpT, b_proj, out);
}